// Round 1
// baseline (681.131 us; speedup 1.0000x reference)
//
#include <hip/hip_runtime.h>
#include <hip/hip_cooperative_groups.h>
#include <math.h>

typedef unsigned short ushort_t;
typedef unsigned int uint_t;

// Problem constants
#define B_      8
#define T_      2048
#define DIMX    512
#define DM      128
#define DINNER  256
#define NSTATE  16
#define HDIM    64
#define NH      4
#define CONVDIM 288
#define PROJ    548
#define KCONV   4
#define LLAYERS 2
#define QCH     128
#define NC      (T_/QCH)
#define EPSF    1e-5f
#define MTOK    (B_*T_)

// ---- workspace layout (float offsets) — identical to round-8 passing build ----
#define OFF_H      0u
#define OFF_PROJ   2097152u
#define OFF_HBC    11075584u
#define OFF_Y      15794176u
#define OFF_DTP    19988480u
#define OFF_CUM    20054016u
#define OFF_Z      20119552u
#define OFF_SPREV  20643840u
#define OFF_DEC    21168128u
#define OFF_PART   21168640u
#define OFF_BF     21299712u
#define OFF_WTIN   23396864u
#define OFF_WTINP  23429632u
#define OFF_WTOUT  23503360u

__device__ __forceinline__ ushort_t f2b(float f) {
    uint_t u = __builtin_bit_cast(uint_t, f);
    return (ushort_t)((u + 0x7FFFu + ((u >> 16) & 1u)) >> 16);
}
__device__ __forceinline__ float b2f(ushort_t b) {
    uint_t u = ((uint_t)b) << 16;
    return __builtin_bit_cast(float, u);
}

typedef short bf8 __attribute__((ext_vector_type(8)));
typedef float f4v __attribute__((ext_vector_type(4)));

// ===== all weight transposes in ONE kernel (proven r8) =====
__global__ __launch_bounds__(256) void k_wt_all(
    const float* __restrict__ in_w, const float* __restrict__ inproj_w,
    const float* __restrict__ outproj_w,
    ushort_t* __restrict__ wt_in, ushort_t* __restrict__ wt_inp,
    ushort_t* __restrict__ wt_out)
{
    __shared__ float tile[64][65];
    int idx = blockIdx.x;
    const float* W; ushort_t* Wt; int K, N, k0, n0;
    if (idx < 16) {
        W = in_w; Wt = wt_in; K = 512; N = 128;
        k0 = (idx & 7) * 64; n0 = (idx >> 3) * 64;
    } else if (idx < 52) {
        int r = idx - 16; int l = r / 18; r -= l * 18;
        W = inproj_w + l * 128 * PROJ; Wt = wt_inp + l * 576 * 128; K = 128; N = PROJ;
        k0 = (r & 1) * 64; n0 = (r >> 1) * 64;
    } else {
        int r = idx - 52; int l = r / 8; r -= l * 8;
        W = outproj_w + l * 256 * 128; Wt = wt_out + l * 128 * 256; K = 256; N = 128;
        k0 = (r & 3) * 64; n0 = (r >> 2) * 64;
    }
    const int tid = threadIdx.x;
#pragma unroll
    for (int it = 0; it < 16; ++it) {
        const int e = it * 256 + tid;
        const int kk = e >> 6, nn = e & 63;
        tile[kk][nn] = (n0 + nn < N) ? W[(k0 + kk) * N + (n0 + nn)] : 0.f;
    }
    __syncthreads();
#pragma unroll
    for (int it = 0; it < 16; ++it) {
        const int e = it * 256 + tid;
        const int nn = e >> 6, kk = e & 63;
        Wt[(n0 + nn) * K + k0 + kk] = f2b(tile[kk][nn]);
    }
}

// ===== MFMA GEMM template (proven r8) =====
// EPI: 0 = plain, 1 = +bias(aux[col]), 2 = += C in place (residual)
template<int KTOT, int LDC, int NGUARD, int EPI, bool ABF16>
__global__ __launch_bounds__(256) void k_gemm(
    const void* __restrict__ Ap, const ushort_t* __restrict__ Bt,
    const float* __restrict__ aux, float* __restrict__ C)
{
    __shared__ ushort_t Als[64 * 136];
    __shared__ ushort_t Bls[64 * 136];
    const int m0 = blockIdx.x * 64, n0 = blockIdx.y * 64;
    const int tid = threadIdx.x;
    const int lane = tid & 63, w = tid >> 6;
    const int wm = (w >> 1) * 32, wn = (w & 1) * 32;
    const int r16 = lane & 15, q8 = (lane >> 4) * 8;

    f4v acc[2][2];
#pragma unroll
    for (int i = 0; i < 2; ++i)
#pragma unroll
        for (int j = 0; j < 2; ++j) acc[i][j] = (f4v)0.f;

    for (int kc = 0; kc < KTOT; kc += 128) {
        if constexpr (ABF16) {
            const ushort_t* A = (const ushort_t*)Ap;
#pragma unroll
            for (int i = 0; i < 4; ++i) {
                const int e = i * 2048 + tid * 8;
                const int r = e >> 7, c = e & 127;
                *(uint4*)&Als[r * 136 + c] = *(const uint4*)&A[(m0 + r) * KTOT + kc + c];
            }
        } else {
            const float* A = (const float*)Ap;
#pragma unroll
            for (int i = 0; i < 4; ++i) {
                const int e = i * 2048 + tid * 8;
                const int r = e >> 7, c = e & 127;
                const float4 f0 = *(const float4*)&A[(m0 + r) * KTOT + kc + c];
                const float4 f1 = *(const float4*)&A[(m0 + r) * KTOT + kc + c + 4];
                uint4 pk;
                pk.x = (uint_t)f2b(f0.x) | ((uint_t)f2b(f0.y) << 16);
                pk.y = (uint_t)f2b(f0.z) | ((uint_t)f2b(f0.w) << 16);
                pk.z = (uint_t)f2b(f1.x) | ((uint_t)f2b(f1.y) << 16);
                pk.w = (uint_t)f2b(f1.z) | ((uint_t)f2b(f1.w) << 16);
                *(uint4*)&Als[r * 136 + c] = pk;
            }
        }
#pragma unroll
        for (int i = 0; i < 4; ++i) {
            const int e = i * 2048 + tid * 8;
            const int r = e >> 7, c = e & 127;
            *(uint4*)&Bls[r * 136 + c] = *(const uint4*)&Bt[(n0 + r) * KTOT + kc + c];
        }
        __syncthreads();
#pragma unroll
        for (int kk = 0; kk < 128; kk += 32) {
            const bf8 a0 = *(const bf8*)&Als[(wm + r16) * 136 + kk + q8];
            const bf8 a1 = *(const bf8*)&Als[(wm + 16 + r16) * 136 + kk + q8];
            const bf8 b0 = *(const bf8*)&Bls[(wn + r16) * 136 + kk + q8];
            const bf8 b1 = *(const bf8*)&Bls[(wn + 16 + r16) * 136 + kk + q8];
            acc[0][0] = __builtin_amdgcn_mfma_f32_16x16x32_bf16(a0, b0, acc[0][0], 0, 0, 0);
            acc[0][1] = __builtin_amdgcn_mfma_f32_16x16x32_bf16(a0, b1, acc[0][1], 0, 0, 0);
            acc[1][0] = __builtin_amdgcn_mfma_f32_16x16x32_bf16(a1, b0, acc[1][0], 0, 0, 0);
            acc[1][1] = __builtin_amdgcn_mfma_f32_16x16x32_bf16(a1, b1, acc[1][1], 0, 0, 0);
        }
        __syncthreads();
    }
    const int q4 = (lane >> 4) * 4;
#pragma unroll
    for (int i = 0; i < 2; ++i)
#pragma unroll
        for (int j = 0; j < 2; ++j)
#pragma unroll
            for (int r = 0; r < 4; ++r) {
                const int grow = m0 + wm + i * 16 + q4 + r;
                const int gcol = n0 + wn + j * 16 + r16;
                if (NGUARD == 0 || gcol < NGUARD) {
                    float v = acc[i][j][r];
                    if (EPI == 1) v += aux[gcol];
                    if (EPI == 2) v += C[grow * LDC + gcol];
                    C[grow * LDC + gcol] = v;
                }
            }
}

// ===== rmsnorm: h (fp32) -> hn (bf16) (proven r8) =====
__global__ __launch_bounds__(256) void k_rmsnorm(
    const float* __restrict__ h, const float* __restrict__ nw,
    ushort_t* __restrict__ hnb)
{
    const int tk = blockIdx.x * 4 + (threadIdx.x >> 6);
    const int lane = threadIdx.x & 63;
    const float2 v = *(const float2*)&h[tk * 128 + lane * 2];
    float s = v.x * v.x + v.y * v.y;
#pragma unroll
    for (int off = 32; off; off >>= 1) s += __shfl_xor(s, off);
    const float rs = rsqrtf(s * (1.f / 128.f) + EPSF);
    const float a = v.x * rs * nw[lane * 2];
    const float b = v.y * rs * nw[lane * 2 + 1];
    ((uint_t*)hnb)[tk * 64 + lane] = (uint_t)f2b(a) | ((uint_t)f2b(b) << 16);
}

// ===== gated rmsnorm -> bf16 (proven r8, fp32 inputs) =====
__global__ __launch_bounds__(256) void k_gnorm(
    const float* __restrict__ y, const float* __restrict__ proj,
    const float* __restrict__ gw, ushort_t* __restrict__ vb)
{
    const int tok = blockIdx.x * 4 + (threadIdx.x >> 6);
    const int lane = threadIdx.x & 63;
    const float4 yv = *(const float4*)&y[tok * 256 + lane * 4];
    const float4 g = *(const float4*)&proj[tok * PROJ + lane * 4];
    float4 v;
    v.x = yv.x * (g.x / (1.f + __expf(-g.x)));
    v.y = yv.y * (g.y / (1.f + __expf(-g.y)));
    v.z = yv.z * (g.z / (1.f + __expf(-g.z)));
    v.w = yv.w * (g.w / (1.f + __expf(-g.w)));
    float s = v.x * v.x + v.y * v.y + v.z * v.z + v.w * v.w;
#pragma unroll
    for (int off = 32; off; off >>= 1) s += __shfl_xor(s, off);
    const float rs = rsqrtf(s * (1.f / 256.f) + EPSF);
    const float4 w4 = *(const float4*)&gw[lane * 4];
    uint2 pk;
    pk.x = (uint_t)f2b(v.x * rs * w4.x) | ((uint_t)f2b(v.y * rs * w4.y) << 16);
    pk.y = (uint_t)f2b(v.z * rs * w4.z) | ((uint_t)f2b(v.w * rs * w4.w) << 16);
    ((uint2*)vb)[tok * 64 + lane] = pk;
}

// ===== conv + dtprep merged (proven) =====
__global__ __launch_bounds__(256) void k_convdt(
    const float* __restrict__ proj, const float* __restrict__ cw,
    const float* __restrict__ cb, const float* __restrict__ A_log,
    const float* __restrict__ dt_bias, float* __restrict__ hbc,
    float* __restrict__ dtp, float* __restrict__ cum, int l)
{
    __shared__ float sc[128];
    const int bid = blockIdx.x;
    const int tid = threadIdx.x;
    if (bid < (MTOK * CONVDIM) / 256) {
        const int e = bid * 256 + tid;
        const int m = e / CONVDIM;
        const int cch = e - m * CONVDIM;
        const int b = m >> 11;
        const int t = m & (T_ - 1);
        const float* wp = cw + (l * CONVDIM + cch) * KCONV;
        float acc = cb[l * CONVDIM + cch];
#pragma unroll
        for (int k = 0; k < KCONV; ++k) {
            const int tt = t - (KCONV - 1) + k;
            if (tt >= 0) acc += proj[(b * T_ + tt) * PROJ + DINNER + cch] * wp[k];
        }
        hbc[m * CONVDIM + cch] = acc / (1.f + __expf(-acc));
    } else {
        const int bid2 = bid - (MTOK * CONVDIM) / 256;
        const int c = bid2 & (NC - 1);
        const int hh = (bid2 / NC) & (NH - 1);
        const int b = bid2 / (NC * NH);
        const int t = tid;
        float dtv = 0.f;
        if (t < 128) {
            const int m = b * T_ + c * QCH + t;
            const float Ah = -expf(A_log[l * NH + hh]);
            const float raw = proj[m * PROJ + DINNER + CONVDIM + hh] + dt_bias[l * NH + hh];
            dtv = (raw > 20.f) ? raw : log1pf(expf(raw));
            sc[t] = dtv * Ah;
        }
        __syncthreads();
        for (int off = 1; off < 128; off <<= 1) {
            const float v = (t >= off && t < 128) ? sc[t - off] : 0.f;
            __syncthreads();
            if (t < 128) sc[t] += v;
            __syncthreads();
        }
        if (t < 128) {
            const int m = b * T_ + c * QCH + t;
            dtp[m * NH + hh] = dtv;
            cum[m * NH + hh] = sc[t];
        }
    }
}

// ===== NEW: fused SSD (state + inter-chunk scan + y) — one cooperative launch.
// Math is bit-identical to r8's k_ssd_state / k_state_scan / k_ssd_y; the
// shared staging (Xt, BlsT, ClsT, cumls, dtls) is done ONCE and lives in LDS
// across the grid.sync()s. LDS total = 77 KB -> exactly 2 blocks/CU -> all
// 512 blocks co-resident (required for grid sync; enforced by launch_bounds).
__global__ __launch_bounds__(256, 2) void k_ssd_fused(
    const float* __restrict__ hbc, const float* __restrict__ dtp,
    const float* __restrict__ cum, const float* __restrict__ Dvec,
    float* __restrict__ zbuf, float* __restrict__ dec,
    float* __restrict__ sprev, float* __restrict__ ybuf, int l)
{
    __shared__ ushort_t Xt[64 * 136];
    __shared__ ushort_t BlsT[128 * 40];
    __shared__ ushort_t ClsT[128 * 40];
    __shared__ ushort_t Gls[128 * 136];   // phase1: wB[16*136]; phase3: G matrix
    __shared__ ushort_t Spt[64 * 40];
    __shared__ float cumls[QCH];
    __shared__ float dtls[QCH];

    const int bid = blockIdx.x;
    const int c = bid & (NC - 1);
    const int hh = (bid / NC) & (NH - 1);
    const int b = bid / (NC * NH);
    const int m0 = b * T_ + c * QCH;
    const int tid = threadIdx.x;

    // ---- stage once (shared by state & y phases) ----
    if (tid < QCH) {
        cumls[tid] = cum[(m0 + tid) * NH + hh];
        dtls[tid] = dtp[(m0 + tid) * NH + hh];
    }
    {
        const int p = tid & 63;
        const int s0 = tid >> 6;
#pragma unroll
        for (int pass = 0; pass < 32; ++pass) {
            const int s = s0 + pass * 4;
            Xt[p * 136 + s] = f2b(hbc[(m0 + s) * CONVDIM + hh * 64 + p]);
        }
    }
    for (int e = tid; e < QCH * 16; e += 256) {
        const int n = e & 15, s = e >> 4;
        BlsT[s * 40 + n] = f2b(hbc[(m0 + s) * CONVDIM + DINNER + n]);
        BlsT[s * 40 + 16 + n] = 0;
        ClsT[s * 40 + n] = f2b(hbc[(m0 + s) * CONVDIM + DINNER + NSTATE + n]);
        ClsT[s * 40 + 16 + n] = 0;
    }
    __syncthreads();
    const float clast = cumls[QCH - 1];

    // ---- phase 1: weighted-B (wB lives in Gls storage), chunk-state MFMA ----
    for (int e = tid; e < QCH * 16; e += 256) {
        const int n = e & 15, s = e >> 4;
        const float w = __expf(clast - cumls[s]) * dtls[s];
        Gls[n * 136 + s] = f2b(w * hbc[(m0 + s) * CONVDIM + DINNER + n]);
    }
    __syncthreads();

    const int lane = tid & 63, w = tid >> 6;
    const int r16 = lane & 15, q8 = (lane >> 4) * 8, q4 = (lane >> 4) * 4;
    {
        f4v acc = (f4v)0.f;
#pragma unroll
        for (int kc = 0; kc < 128; kc += 32) {
            const bf8 a = *(const bf8*)&Xt[(w * 16 + r16) * 136 + kc + q8];
            const bf8 bb = *(const bf8*)&Gls[r16 * 136 + kc + q8];
            acc = __builtin_amdgcn_mfma_f32_16x16x32_bf16(a, bb, acc, 0, 0, 0);
        }
#pragma unroll
        for (int r = 0; r < 4; ++r) {
            const int p = w * 16 + q4 + r;
            zbuf[bid * 1024 + p * 16 + r16] = acc[r];
        }
        if (tid == 0) dec[bid] = __expf(clast);
    }

    __threadfence();
    cooperative_groups::this_grid().sync();

    // ---- phase 2: inter-chunk state scan (first 32 blocks) ----
    if (bid < B_ * NH) {
        float4 S; S.x = 0.f; S.y = 0.f; S.z = 0.f; S.w = 0.f;
        for (int cc = 0; cc < NC; ++cc) {
            const int idx = (bid * NC + cc) * 1024 + tid * 4;
            *(float4*)(sprev + idx) = S;
            const float d = dec[bid * NC + cc];
            const float4 z = *(const float4*)(zbuf + idx);
            S.x = S.x * d + z.x; S.y = S.y * d + z.y;
            S.z = S.z * d + z.z; S.w = S.w * d + z.w;
        }
    }

    __threadfence();
    cooperative_groups::this_grid().sync();

    // ---- phase 3: y (identical to r8 k_ssd_y; Xt/BlsT/ClsT/cum/dt reused) ----
    for (int e = tid; e < 1024; e += 256) {
        const int n = e & 15, p = e >> 4;
        Spt[p * 40 + n] = f2b(sprev[bid * 1024 + p * 16 + n]);
        Spt[p * 40 + 16 + n] = 0;
    }
    __syncthreads();

    const int wrow = w * 32;
    const float Dh = Dvec[l * NH + hh];

    bf8 cfr[2];
#pragma unroll
    for (int i = 0; i < 2; ++i)
        cfr[i] = *(const bf8*)&ClsT[(wrow + i * 16 + r16) * 40 + q8];

    float cumt[8], et[8];
#pragma unroll
    for (int i = 0; i < 2; ++i)
#pragma unroll
        for (int r = 0; r < 4; ++r) {
            const int t = wrow + i * 16 + q4 + r;
            cumt[i * 4 + r] = cumls[t];
            et[i * 4 + r] = __expf(cumls[t]);
        }

    f4v acc2[2][4];
#pragma unroll
    for (int j = 0; j < 4; ++j) {
        const bf8 sf = *(const bf8*)&Spt[(j * 16 + r16) * 40 + q8];
#pragma unroll
        for (int i = 0; i < 2; ++i) {
            f4v z = (f4v)0.f;
            z = __builtin_amdgcn_mfma_f32_16x16x32_bf16(cfr[i], sf, z, 0, 0, 0);
#pragma unroll
            for (int r = 0; r < 4; ++r) {
                const int t = wrow + i * 16 + q4 + r;
                const int p = j * 16 + r16;
                acc2[i][j][r] = z[r] * et[i * 4 + r] + Dh * b2f(Xt[p * 136 + t]);
            }
        }
    }

#pragma unroll
    for (int ts = 0; ts < 8; ++ts) {
        const bf8 bf = *(const bf8*)&BlsT[(ts * 16 + r16) * 40 + q8];
        const int s = ts * 16 + r16;
        const float cs = cumls[s];
        const float ds = dtls[s];
#pragma unroll
        for (int i = 0; i < 2; ++i) {
            f4v g = (f4v)0.f;
            g = __builtin_amdgcn_mfma_f32_16x16x32_bf16(cfr[i], bf, g, 0, 0, 0);
#pragma unroll
            for (int r = 0; r < 4; ++r) {
                const int t = wrow + i * 16 + q4 + r;
                const float val = (s <= t) ? __expf(cumt[i * 4 + r] - cs) * ds * g[r] : 0.f;
                Gls[t * 136 + s] = f2b(val);
            }
        }
    }
    __syncthreads();

#pragma unroll
    for (int kc = 0; kc < 128; kc += 32) {
        bf8 af[2];
#pragma unroll
        for (int i = 0; i < 2; ++i)
            af[i] = *(const bf8*)&Gls[(wrow + i * 16 + r16) * 136 + kc + q8];
#pragma unroll
        for (int j = 0; j < 4; ++j) {
            const bf8 xf = *(const bf8*)&Xt[(j * 16 + r16) * 136 + kc + q8];
#pragma unroll
            for (int i = 0; i < 2; ++i)
                acc2[i][j] = __builtin_amdgcn_mfma_f32_16x16x32_bf16(af[i], xf, acc2[i][j], 0, 0, 0);
        }
    }

#pragma unroll
    for (int i = 0; i < 2; ++i)
#pragma unroll
        for (int r = 0; r < 4; ++r) {
            const int t = wrow + i * 16 + q4 + r;
#pragma unroll
            for (int j = 0; j < 4; ++j) {
                const int p = j * 16 + r16;
                ybuf[(m0 + t) * DINNER + hh * 64 + p] = acc2[i][j][r];
            }
        }
}

// ===== legacy SSD kernels kept as fallback if cooperative launch unavailable =====
__global__ __launch_bounds__(256) void k_ssd_state(
    const float* __restrict__ hbc, const float* __restrict__ dtp,
    const float* __restrict__ cum, float* __restrict__ zbuf,
    float* __restrict__ dec)
{
    __shared__ ushort_t Xt[64 * 136];
    __shared__ ushort_t wB[16 * 136];
    __shared__ float cumls[QCH];
    __shared__ float dtls[QCH];
    const int bid = blockIdx.x;
    const int c = bid & (NC - 1);
    const int hh = (bid / NC) & (NH - 1);
    const int b = bid / (NC * NH);
    const int m0 = b * T_ + c * QCH;
    const int tid = threadIdx.x;

    if (tid < QCH) {
        cumls[tid] = cum[(m0 + tid) * NH + hh];
        dtls[tid] = dtp[(m0 + tid) * NH + hh];
    }
    __syncthreads();
    const float clast = cumls[QCH - 1];
    {
        const int p = tid & 63;
        const int s0 = tid >> 6;
#pragma unroll
        for (int pass = 0; pass < 32; ++pass) {
            const int s = s0 + pass * 4;
            Xt[p * 136 + s] = f2b(hbc[(m0 + s) * CONVDIM + hh * 64 + p]);
        }
    }
    for (int e = tid; e < QCH * 16; e += 256) {
        const int n = e & 15, s = e >> 4;
        const float w = __expf(clast - cumls[s]) * dtls[s];
        wB[n * 136 + s] = f2b(w * hbc[(m0 + s) * CONVDIM + DINNER + n]);
    }
    __syncthreads();

    const int lane = tid & 63, w = tid >> 6;
    const int r16 = lane & 15, q8 = (lane >> 4) * 8, q4 = (lane >> 4) * 4;
    f4v acc = (f4v)0.f;
#pragma unroll
    for (int kc = 0; kc < 128; kc += 32) {
        const bf8 a = *(const bf8*)&Xt[(w * 16 + r16) * 136 + kc + q8];
        const bf8 bb = *(const bf8*)&wB[r16 * 136 + kc + q8];
        acc = __builtin_amdgcn_mfma_f32_16x16x32_bf16(a, bb, acc, 0, 0, 0);
    }
#pragma unroll
    for (int r = 0; r < 4; ++r) {
        const int p = w * 16 + q4 + r;
        zbuf[bid * 1024 + p * 16 + r16] = acc[r];
    }
    if (tid == 0) dec[bid] = __expf(clast);
}

__global__ __launch_bounds__(256) void k_state_scan(
    const float* __restrict__ zbuf, const float* __restrict__ dec,
    float* __restrict__ sprev)
{
    const int bh = blockIdx.x;
    const int tid = threadIdx.x;
    float4 S; S.x = 0.f; S.y = 0.f; S.z = 0.f; S.w = 0.f;
    for (int c = 0; c < NC; ++c) {
        const int idx = (bh * NC + c) * 1024 + tid * 4;
        *(float4*)(sprev + idx) = S;
        const float d = dec[bh * NC + c];
        const float4 z = *(const float4*)(zbuf + idx);
        S.x = S.x * d + z.x; S.y = S.y * d + z.y;
        S.z = S.z * d + z.z; S.w = S.w * d + z.w;
    }
}

__global__ __launch_bounds__(256) void k_ssd_y(
    const float* __restrict__ hbc, const float* __restrict__ dtp,
    const float* __restrict__ cum, const float* __restrict__ sprev,
    const float* __restrict__ Dvec, float* __restrict__ ybuf, int l)
{
    __shared__ ushort_t Xt[64 * 136];
    __shared__ ushort_t BlsT[128 * 40];
    __shared__ ushort_t ClsT[128 * 40];
    __shared__ ushort_t Gls[128 * 136];
    __shared__ ushort_t Spt[64 * 40];
    __shared__ float cumls[QCH];
    __shared__ float dtls[QCH];
    const int bid = blockIdx.x;
    const int c = bid & (NC - 1);
    const int hh = (bid / NC) & (NH - 1);
    const int b = bid / (NC * NH);
    const int m0 = b * T_ + c * QCH;
    const int tid = threadIdx.x;

    if (tid < QCH) {
        cumls[tid] = cum[(m0 + tid) * NH + hh];
        dtls[tid] = dtp[(m0 + tid) * NH + hh];
    }
    {
        const int p = tid & 63;
        const int s0 = tid >> 6;
#pragma unroll
        for (int pass = 0; pass < 32; ++pass) {
            const int s = s0 + pass * 4;
            Xt[p * 136 + s] = f2b(hbc[(m0 + s) * CONVDIM + hh * 64 + p]);
        }
    }
    for (int e = tid; e < QCH * 16; e += 256) {
        const int n = e & 15, s = e >> 4;
        BlsT[s * 40 + n] = f2b(hbc[(m0 + s) * CONVDIM + DINNER + n]);
        BlsT[s * 40 + 16 + n] = 0;
        ClsT[s * 40 + n] = f2b(hbc[(m0 + s) * CONVDIM + DINNER + NSTATE + n]);
        ClsT[s * 40 + 16 + n] = 0;
    }
    for (int e = tid; e < 1024; e += 256) {
        const int n = e & 15, p = e >> 4;
        Spt[p * 40 + n] = f2b(sprev[bid * 1024 + p * 16 + n]);
        Spt[p * 40 + 16 + n] = 0;
    }
    __syncthreads();

    const int lane = tid & 63, w = tid >> 6;
    const int wrow = w * 32;
    const int r16 = lane & 15, q8 = (lane >> 4) * 8, q4 = (lane >> 4) * 4;
    const float Dh = Dvec[l * NH + hh];

    bf8 cfr[2];
#pragma unroll
    for (int i = 0; i < 2; ++i)
        cfr[i] = *(const bf8*)&ClsT[(wrow + i * 16 + r16) * 40 + q8];

    float cumt[8], et[8];
#pragma unroll
    for (int i = 0; i < 2; ++i)
#pragma unroll
        for (int r = 0; r < 4; ++r) {
            const int t = wrow + i * 16 + q4 + r;
            cumt[i * 4 + r] = cumls[t];
            et[i * 4 + r] = __expf(cumls[t]);
        }

    f4v acc[2][4];
#pragma unroll
    for (int j = 0; j < 4; ++j) {
        const bf8 sf = *(const bf8*)&Spt[(j * 16 + r16) * 40 + q8];
#pragma unroll
        for (int i = 0; i < 2; ++i) {
            f4v z = (f4v)0.f;
            z = __builtin_amdgcn_mfma_f32_16x16x32_bf16(cfr[i], sf, z, 0, 0, 0);
#pragma unroll
            for (int r = 0; r < 4; ++r) {
                const int t = wrow + i * 16 + q4 + r;
                const int p = j * 16 + r16;
                acc[i][j][r] = z[r] * et[i * 4 + r] + Dh * b2f(Xt[p * 136 + t]);
            }
        }
    }

#pragma unroll
    for (int ts = 0; ts < 8; ++ts) {
        const bf8 bf = *(const bf8*)&BlsT[(ts * 16 + r16) * 40 + q8];
        const int s = ts * 16 + r16;
        const float cs = cumls[s];
        const float ds = dtls[s];
#pragma unroll
        for (int i = 0; i < 2; ++i) {
            f4v g = (f4v)0.f;
            g = __builtin_amdgcn_mfma_f32_16x16x32_bf16(cfr[i], bf, g, 0, 0, 0);
#pragma unroll
            for (int r = 0; r < 4; ++r) {
                const int t = wrow + i * 16 + q4 + r;
                const float val = (s <= t) ? __expf(cumt[i * 4 + r] - cs) * ds * g[r] : 0.f;
                Gls[t * 136 + s] = f2b(val);
            }
        }
    }
    __syncthreads();

#pragma unroll
    for (int kc = 0; kc < 128; kc += 32) {
        bf8 af[2];
#pragma unroll
        for (int i = 0; i < 2; ++i)
            af[i] = *(const bf8*)&Gls[(wrow + i * 16 + r16) * 136 + kc + q8];
#pragma unroll
        for (int j = 0; j < 4; ++j) {
            const bf8 xf = *(const bf8*)&Xt[(j * 16 + r16) * 136 + kc + q8];
#pragma unroll
            for (int i = 0; i < 2; ++i)
                acc[i][j] = __builtin_amdgcn_mfma_f32_16x16x32_bf16(af[i], xf, acc[i][j], 0, 0, 0);
        }
    }

#pragma unroll
    for (int i = 0; i < 2; ++i)
#pragma unroll
        for (int r = 0; r < 4; ++r) {
            const int t = wrow + i * 16 + q4 + r;
#pragma unroll
            for (int j = 0; j < 4; ++j) {
                const int p = j * 16 + r16;
                ybuf[(m0 + t) * DINNER + hh * 64 + p] = acc[i][j][r];
            }
        }
}

// ===== final rmsnorm + partial mean-pool (proven) =====
__global__ __launch_bounds__(256) void k_finalnorm_pool(
    const float* __restrict__ h, const float* __restrict__ nfw,
    float* __restrict__ part)
{
    __shared__ float ht[2048];
    __shared__ float red[256];
    __shared__ float rstd[16];
    __shared__ float padd[256];
    const int tile = blockIdx.x & 127;
    const int b = blockIdx.x >> 7;
    const int m0 = b * T_ + tile * 16;
    const int tid = threadIdx.x;
    for (int e = tid; e < 2048; e += 256) ht[e] = h[m0 * DM + e];
    __syncthreads();
    {
        const int tg = tid >> 4, j0 = tid & 15;
        float p = 0.f;
#pragma unroll
        for (int k = 0; k < 8; ++k) { const float v = ht[tg * 128 + j0 + 16 * k]; p += v * v; }
        red[tid] = p;
    }
    __syncthreads();
    if (tid < 16) {
        float s = 0.f;
#pragma unroll
        for (int q = 0; q < 16; ++q) s += red[tid * 16 + q];
        rstd[tid] = rsqrtf(s * (1.f / 128.f) + EPSF);
    }
    __syncthreads();
    const int d = tid & 127, half = tid >> 7;
    float ps = 0.f;
#pragma unroll
    for (int i0 = 0; i0 < 8; ++i0) { const int i = half + 2 * i0; ps += ht[i * 128 + d] * rstd[i]; }
    padd[tid] = ps;
    __syncthreads();
    if (tid < 128) part[(b * 128 + tile) * 128 + tid] = (padd[tid] + padd[128 + tid]) * nfw[tid];
}

// ===== pooled reduce + head GEMM (proven) =====
__global__ __launch_bounds__(256) void k_head(
    const float* __restrict__ part, const float* __restrict__ ow,
    const float* __restrict__ ob, float* __restrict__ out)
{
    __shared__ float pooled[128];
    const int b = blockIdx.x;
    const int tid = threadIdx.x;
    if (tid < 128) {
        float s = 0.f;
        for (int tile = 0; tile < 128; ++tile) s += part[(b * 128 + tile) * 128 + tid];
        pooled[tid] = s * (1.f / (float)T_);
    }
    __syncthreads();
    for (int o = tid; o < DIMX; o += 256) {
        float acc = ob[o];
#pragma unroll 4
        for (int d = 0; d < 128; ++d) acc += pooled[d] * ow[d * DIMX + o];
        out[b * DIMX + o] = acc;
    }
}

extern "C" void kernel_launch(void* const* d_in, const int* in_sizes, int n_in,
                              void* d_out, int out_size, void* d_ws, size_t ws_size,
                              hipStream_t stream)
{
    const float* x         = (const float*)d_in[0];
    const float* in_w      = (const float*)d_in[1];
    const float* in_b      = (const float*)d_in[2];
    const float* norm_w    = (const float*)d_in[3];
    const float* inproj_w  = (const float*)d_in[4];
    const float* conv_w    = (const float*)d_in[5];
    const float* conv_b    = (const float*)d_in[6];
    const float* A_log     = (const float*)d_in[7];
    const float* Dvec      = (const float*)d_in[8];
    const float* dt_bias   = (const float*)d_in[9];
    const float* gnorm_w   = (const float*)d_in[10];
    const float* outproj_w = (const float*)d_in[11];
    const float* normf_w   = (const float*)d_in[12];
    const float* out_w     = (const float*)d_in[13];
    const float* out_b     = (const float*)d_in[14];

    float* ws    = (float*)d_ws;
    float* h     = ws + OFF_H;
    float* proj  = ws + OFF_PROJ;
    float* hbc   = ws + OFF_HBC;
    float* ybuf  = ws + OFF_Y;
    float* dtp   = ws + OFF_DTP;
    float* cumb  = ws + OFF_CUM;
    float* zbuf  = ws + OFF_Z;
    float* sprev = ws + OFF_SPREV;
    float* dec   = ws + OFF_DEC;
    float* part  = ws + OFF_PART;
    ushort_t* bf_scr = (ushort_t*)(ws + OFF_BF);
    ushort_t* wt_in  = (ushort_t*)(ws + OFF_WTIN);
    ushort_t* wt_inp = (ushort_t*)(ws + OFF_WTINP);
    ushort_t* wt_out = (ushort_t*)(ws + OFF_WTOUT);

    // one-time check: does this device support cooperative launch? (host-side
    // attribute query, not a stream op — safe under graph capture)
    static int coop = -1;
    if (coop < 0) {
        int dev = 0; hipGetDevice(&dev);
        int v = 0;
        if (hipDeviceGetAttribute(&v, hipDeviceAttributeCooperativeLaunch, dev) != hipSuccess) v = 1;
        coop = v;
    }

    k_wt_all<<<68, 256, 0, stream>>>(in_w, inproj_w, outproj_w, wt_in, wt_inp, wt_out);

    k_gemm<512, 128, 0, 1, false><<<dim3(MTOK / 64, 2), 256, 0, stream>>>(x, wt_in, in_b, h);

    for (int l = 0; l < LLAYERS; ++l) {
        k_rmsnorm<<<MTOK / 4, 256, 0, stream>>>(h, norm_w + l * DM, bf_scr);
        k_gemm<128, PROJ, PROJ, 0, true><<<dim3(MTOK / 64, 9), 256, 0, stream>>>(
            bf_scr, wt_inp + l * 576 * 128, nullptr, proj);
        k_convdt<<<(MTOK * CONVDIM) / 256 + B_ * NH * NC, 256, 0, stream>>>(
            proj, conv_w, conv_b, A_log, dt_bias, hbc, dtp, cumb, l);

        bool done = false;
        if (coop) {
            int ll = l;
            void* args[] = { (void*)&hbc, (void*)&dtp, (void*)&cumb, (void*)&Dvec,
                             (void*)&zbuf, (void*)&dec, (void*)&sprev, (void*)&ybuf,
                             (void*)&ll };
            if (hipLaunchCooperativeKernel(k_ssd_fused, dim3(B_ * NH * NC), dim3(256),
                                           args, 0, stream) == hipSuccess) {
                done = true;
            } else {
                coop = 0;
            }
        }
        if (!done) {
            k_ssd_state<<<B_ * NH * NC, 256, 0, stream>>>(hbc, dtp, cumb, zbuf, dec);
            k_state_scan<<<B_ * NH, 256, 0, stream>>>(zbuf, dec, sprev);
            k_ssd_y<<<B_ * NH * NC, 256, 0, stream>>>(hbc, dtp, cumb, sprev, Dvec, ybuf, l);
        }

        k_gnorm<<<MTOK / 4, 256, 0, stream>>>(ybuf, proj, gnorm_w + l * DINNER, bf_scr);
        k_gemm<256, 128, 0, 2, true><<<dim3(MTOK / 64, 2), 256, 0, stream>>>(
            bf_scr, wt_out + l * 128 * 256, nullptr, h);
    }

    k_finalnorm_pool<<<B_ * (T_ / 16), 256, 0, stream>>>(h, normf_w, part);
    k_head<<<B_, 256, 0, stream>>>(part, out_w, out_b, (float*)d_out);
}

// Round 2
// 299.416 us; speedup vs baseline: 2.2749x; 2.2749x over previous
//
#include <hip/hip_runtime.h>
#include <math.h>

typedef unsigned short ushort_t;
typedef unsigned int uint_t;

// Problem constants
#define B_      8
#define T_      2048
#define DIMX    512
#define DM      128
#define DINNER  256
#define NSTATE  16
#define HDIM    64
#define NH      4
#define CONVDIM 288
#define PROJ    548
#define KCONV   4
#define LLAYERS 2
#define QCH     128
#define NC      (T_/QCH)
#define EPSF    1e-5f
#define MTOK    (B_*T_)

// ---- workspace layout (float offsets) — identical to round-8 passing build ----
#define OFF_H      0u
#define OFF_PROJ   2097152u
#define OFF_HBC    11075584u
#define OFF_Y      15794176u
#define OFF_DTP    19988480u
#define OFF_CUM    20054016u
#define OFF_Z      20119552u
#define OFF_SPREV  20643840u
#define OFF_DEC    21168128u
#define OFF_PART   21168640u
#define OFF_BF     21299712u
#define OFF_WTIN   23396864u
#define OFF_WTINP  23429632u
#define OFF_WTOUT  23503360u

__device__ __forceinline__ ushort_t f2b(float f) {
    uint_t u = __builtin_bit_cast(uint_t, f);
    return (ushort_t)((u + 0x7FFFu + ((u >> 16) & 1u)) >> 16);
}
__device__ __forceinline__ float b2f(ushort_t b) {
    uint_t u = ((uint_t)b) << 16;
    return __builtin_bit_cast(float, u);
}

typedef short bf8 __attribute__((ext_vector_type(8)));
typedef float f4v __attribute__((ext_vector_type(4)));

// ===== all weight transposes in ONE kernel (proven r8) =====
__global__ __launch_bounds__(256) void k_wt_all(
    const float* __restrict__ in_w, const float* __restrict__ inproj_w,
    const float* __restrict__ outproj_w,
    ushort_t* __restrict__ wt_in, ushort_t* __restrict__ wt_inp,
    ushort_t* __restrict__ wt_out)
{
    __shared__ float tile[64][65];
    int idx = blockIdx.x;
    const float* W; ushort_t* Wt; int K, N, k0, n0;
    if (idx < 16) {
        W = in_w; Wt = wt_in; K = 512; N = 128;
        k0 = (idx & 7) * 64; n0 = (idx >> 3) * 64;
    } else if (idx < 52) {
        int r = idx - 16; int l = r / 18; r -= l * 18;
        W = inproj_w + l * 128 * PROJ; Wt = wt_inp + l * 576 * 128; K = 128; N = PROJ;
        k0 = (r & 1) * 64; n0 = (r >> 1) * 64;
    } else {
        int r = idx - 52; int l = r / 8; r -= l * 8;
        W = outproj_w + l * 256 * 128; Wt = wt_out + l * 128 * 256; K = 256; N = 128;
        k0 = (r & 3) * 64; n0 = (r >> 2) * 64;
    }
    const int tid = threadIdx.x;
#pragma unroll
    for (int it = 0; it < 16; ++it) {
        const int e = it * 256 + tid;
        const int kk = e >> 6, nn = e & 63;
        tile[kk][nn] = (n0 + nn < N) ? W[(k0 + kk) * N + (n0 + nn)] : 0.f;
    }
    __syncthreads();
#pragma unroll
    for (int it = 0; it < 16; ++it) {
        const int e = it * 256 + tid;
        const int nn = e >> 6, kk = e & 63;
        Wt[(n0 + nn) * K + k0 + kk] = f2b(tile[kk][nn]);
    }
}

// ===== MFMA GEMM template (proven r8) =====
// EPI: 0 = plain, 1 = +bias(aux[col]), 2 = += C in place (residual)
template<int KTOT, int LDC, int NGUARD, int EPI, bool ABF16>
__global__ __launch_bounds__(256) void k_gemm(
    const void* __restrict__ Ap, const ushort_t* __restrict__ Bt,
    const float* __restrict__ aux, float* __restrict__ C)
{
    __shared__ ushort_t Als[64 * 136];
    __shared__ ushort_t Bls[64 * 136];
    const int m0 = blockIdx.x * 64, n0 = blockIdx.y * 64;
    const int tid = threadIdx.x;
    const int lane = tid & 63, w = tid >> 6;
    const int wm = (w >> 1) * 32, wn = (w & 1) * 32;
    const int r16 = lane & 15, q8 = (lane >> 4) * 8;

    f4v acc[2][2];
#pragma unroll
    for (int i = 0; i < 2; ++i)
#pragma unroll
        for (int j = 0; j < 2; ++j) acc[i][j] = (f4v)0.f;

    for (int kc = 0; kc < KTOT; kc += 128) {
        if constexpr (ABF16) {
            const ushort_t* A = (const ushort_t*)Ap;
#pragma unroll
            for (int i = 0; i < 4; ++i) {
                const int e = i * 2048 + tid * 8;
                const int r = e >> 7, c = e & 127;
                *(uint4*)&Als[r * 136 + c] = *(const uint4*)&A[(m0 + r) * KTOT + kc + c];
            }
        } else {
            const float* A = (const float*)Ap;
#pragma unroll
            for (int i = 0; i < 4; ++i) {
                const int e = i * 2048 + tid * 8;
                const int r = e >> 7, c = e & 127;
                const float4 f0 = *(const float4*)&A[(m0 + r) * KTOT + kc + c];
                const float4 f1 = *(const float4*)&A[(m0 + r) * KTOT + kc + c + 4];
                uint4 pk;
                pk.x = (uint_t)f2b(f0.x) | ((uint_t)f2b(f0.y) << 16);
                pk.y = (uint_t)f2b(f0.z) | ((uint_t)f2b(f0.w) << 16);
                pk.z = (uint_t)f2b(f1.x) | ((uint_t)f2b(f1.y) << 16);
                pk.w = (uint_t)f2b(f1.z) | ((uint_t)f2b(f1.w) << 16);
                *(uint4*)&Als[r * 136 + c] = pk;
            }
        }
#pragma unroll
        for (int i = 0; i < 4; ++i) {
            const int e = i * 2048 + tid * 8;
            const int r = e >> 7, c = e & 127;
            *(uint4*)&Bls[r * 136 + c] = *(const uint4*)&Bt[(n0 + r) * KTOT + kc + c];
        }
        __syncthreads();
#pragma unroll
        for (int kk = 0; kk < 128; kk += 32) {
            const bf8 a0 = *(const bf8*)&Als[(wm + r16) * 136 + kk + q8];
            const bf8 a1 = *(const bf8*)&Als[(wm + 16 + r16) * 136 + kk + q8];
            const bf8 b0 = *(const bf8*)&Bls[(wn + r16) * 136 + kk + q8];
            const bf8 b1 = *(const bf8*)&Bls[(wn + 16 + r16) * 136 + kk + q8];
            acc[0][0] = __builtin_amdgcn_mfma_f32_16x16x32_bf16(a0, b0, acc[0][0], 0, 0, 0);
            acc[0][1] = __builtin_amdgcn_mfma_f32_16x16x32_bf16(a0, b1, acc[0][1], 0, 0, 0);
            acc[1][0] = __builtin_amdgcn_mfma_f32_16x16x32_bf16(a1, b0, acc[1][0], 0, 0, 0);
            acc[1][1] = __builtin_amdgcn_mfma_f32_16x16x32_bf16(a1, b1, acc[1][1], 0, 0, 0);
        }
        __syncthreads();
    }
    const int q4 = (lane >> 4) * 4;
#pragma unroll
    for (int i = 0; i < 2; ++i)
#pragma unroll
        for (int j = 0; j < 2; ++j)
#pragma unroll
            for (int r = 0; r < 4; ++r) {
                const int grow = m0 + wm + i * 16 + q4 + r;
                const int gcol = n0 + wn + j * 16 + r16;
                if (NGUARD == 0 || gcol < NGUARD) {
                    float v = acc[i][j][r];
                    if (EPI == 1) v += aux[gcol];
                    if (EPI == 2) v += C[grow * LDC + gcol];
                    C[grow * LDC + gcol] = v;
                }
            }
}

// ===== rmsnorm: h (fp32) -> hn (bf16) (proven r8) =====
__global__ __launch_bounds__(256) void k_rmsnorm(
    const float* __restrict__ h, const float* __restrict__ nw,
    ushort_t* __restrict__ hnb)
{
    const int tk = blockIdx.x * 4 + (threadIdx.x >> 6);
    const int lane = threadIdx.x & 63;
    const float2 v = *(const float2*)&h[tk * 128 + lane * 2];
    float s = v.x * v.x + v.y * v.y;
#pragma unroll
    for (int off = 32; off; off >>= 1) s += __shfl_xor(s, off);
    const float rs = rsqrtf(s * (1.f / 128.f) + EPSF);
    const float a = v.x * rs * nw[lane * 2];
    const float b = v.y * rs * nw[lane * 2 + 1];
    ((uint_t*)hnb)[tk * 64 + lane] = (uint_t)f2b(a) | ((uint_t)f2b(b) << 16);
}

// ===== gated rmsnorm -> bf16 (proven r8, fp32 inputs) =====
__global__ __launch_bounds__(256) void k_gnorm(
    const float* __restrict__ y, const float* __restrict__ proj,
    const float* __restrict__ gw, ushort_t* __restrict__ vb)
{
    const int tok = blockIdx.x * 4 + (threadIdx.x >> 6);
    const int lane = threadIdx.x & 63;
    const float4 yv = *(const float4*)&y[tok * 256 + lane * 4];
    const float4 g = *(const float4*)&proj[tok * PROJ + lane * 4];
    float4 v;
    v.x = yv.x * (g.x / (1.f + __expf(-g.x)));
    v.y = yv.y * (g.y / (1.f + __expf(-g.y)));
    v.z = yv.z * (g.z / (1.f + __expf(-g.z)));
    v.w = yv.w * (g.w / (1.f + __expf(-g.w)));
    float s = v.x * v.x + v.y * v.y + v.z * v.z + v.w * v.w;
#pragma unroll
    for (int off = 32; off; off >>= 1) s += __shfl_xor(s, off);
    const float rs = rsqrtf(s * (1.f / 256.f) + EPSF);
    const float4 w4 = *(const float4*)&gw[lane * 4];
    uint2 pk;
    pk.x = (uint_t)f2b(v.x * rs * w4.x) | ((uint_t)f2b(v.y * rs * w4.y) << 16);
    pk.y = (uint_t)f2b(v.z * rs * w4.z) | ((uint_t)f2b(v.w * rs * w4.w) << 16);
    ((uint2*)vb)[tok * 64 + lane] = pk;
}

// ===== conv + dtprep merged (proven) =====
__global__ __launch_bounds__(256) void k_convdt(
    const float* __restrict__ proj, const float* __restrict__ cw,
    const float* __restrict__ cb, const float* __restrict__ A_log,
    const float* __restrict__ dt_bias, float* __restrict__ hbc,
    float* __restrict__ dtp, float* __restrict__ cum, int l)
{
    __shared__ float sc[128];
    const int bid = blockIdx.x;
    const int tid = threadIdx.x;
    if (bid < (MTOK * CONVDIM) / 256) {
        const int e = bid * 256 + tid;
        const int m = e / CONVDIM;
        const int cch = e - m * CONVDIM;
        const int b = m >> 11;
        const int t = m & (T_ - 1);
        const float* wp = cw + (l * CONVDIM + cch) * KCONV;
        float acc = cb[l * CONVDIM + cch];
#pragma unroll
        for (int k = 0; k < KCONV; ++k) {
            const int tt = t - (KCONV - 1) + k;
            if (tt >= 0) acc += proj[(b * T_ + tt) * PROJ + DINNER + cch] * wp[k];
        }
        hbc[m * CONVDIM + cch] = acc / (1.f + __expf(-acc));
    } else {
        const int bid2 = bid - (MTOK * CONVDIM) / 256;
        const int c = bid2 & (NC - 1);
        const int hh = (bid2 / NC) & (NH - 1);
        const int b = bid2 / (NC * NH);
        const int t = tid;
        float dtv = 0.f;
        if (t < 128) {
            const int m = b * T_ + c * QCH + t;
            const float Ah = -expf(A_log[l * NH + hh]);
            const float raw = proj[m * PROJ + DINNER + CONVDIM + hh] + dt_bias[l * NH + hh];
            dtv = (raw > 20.f) ? raw : log1pf(expf(raw));
            sc[t] = dtv * Ah;
        }
        __syncthreads();
        for (int off = 1; off < 128; off <<= 1) {
            const float v = (t >= off && t < 128) ? sc[t - off] : 0.f;
            __syncthreads();
            if (t < 128) sc[t] += v;
            __syncthreads();
        }
        if (t < 128) {
            const int m = b * T_ + c * QCH + t;
            dtp[m * NH + hh] = dtv;
            cum[m * NH + hh] = sc[t];
        }
    }
}

// ===== SSD chunk state (proven r8) =====
__global__ __launch_bounds__(256) void k_ssd_state(
    const float* __restrict__ hbc, const float* __restrict__ dtp,
    const float* __restrict__ cum, float* __restrict__ zbuf,
    float* __restrict__ dec)
{
    __shared__ ushort_t Xt[64 * 136];
    __shared__ ushort_t wB[16 * 136];
    __shared__ float cumls[QCH];
    __shared__ float dtls[QCH];
    const int bid = blockIdx.x;
    const int c = bid & (NC - 1);
    const int hh = (bid / NC) & (NH - 1);
    const int b = bid / (NC * NH);
    const int m0 = b * T_ + c * QCH;
    const int tid = threadIdx.x;

    if (tid < QCH) {
        cumls[tid] = cum[(m0 + tid) * NH + hh];
        dtls[tid] = dtp[(m0 + tid) * NH + hh];
    }
    __syncthreads();
    const float clast = cumls[QCH - 1];
    {
        const int p = tid & 63;
        const int s0 = tid >> 6;
#pragma unroll
        for (int pass = 0; pass < 32; ++pass) {
            const int s = s0 + pass * 4;
            Xt[p * 136 + s] = f2b(hbc[(m0 + s) * CONVDIM + hh * 64 + p]);
        }
    }
    for (int e = tid; e < QCH * 16; e += 256) {
        const int n = e & 15, s = e >> 4;
        const float w = __expf(clast - cumls[s]) * dtls[s];
        wB[n * 136 + s] = f2b(w * hbc[(m0 + s) * CONVDIM + DINNER + n]);
    }
    __syncthreads();

    const int lane = tid & 63, w = tid >> 6;
    const int r16 = lane & 15, q8 = (lane >> 4) * 8, q4 = (lane >> 4) * 4;
    f4v acc = (f4v)0.f;
#pragma unroll
    for (int kc = 0; kc < 128; kc += 32) {
        const bf8 a = *(const bf8*)&Xt[(w * 16 + r16) * 136 + kc + q8];
        const bf8 bb = *(const bf8*)&wB[r16 * 136 + kc + q8];
        acc = __builtin_amdgcn_mfma_f32_16x16x32_bf16(a, bb, acc, 0, 0, 0);
    }
#pragma unroll
    for (int r = 0; r < 4; ++r) {
        const int p = w * 16 + q4 + r;
        zbuf[bid * 1024 + p * 16 + r16] = acc[r];
    }
    if (tid == 0) dec[bid] = __expf(clast);
}

// ===== fused SSD y + per-block inter-chunk scan =====
// The launch boundary after k_ssd_state guarantees zbuf/dec complete. Each
// block recomputes the prefix state for its chunk from zbuf/dec with the
// EXACT recurrence/op-order of the old k_state_scan (bit-identical fp32),
// then f2b's it into LDS. Removes the 32-block k_state_scan launch and the
// sprev global round-trip. Redundant zbuf re-reads (~17 MB total) are
// L2/LLC-resident.
__global__ __launch_bounds__(256) void k_ssd_y(
    const float* __restrict__ hbc, const float* __restrict__ dtp,
    const float* __restrict__ cum, const float* __restrict__ zbuf,
    const float* __restrict__ dec, const float* __restrict__ Dvec,
    float* __restrict__ ybuf, int l)
{
    __shared__ ushort_t Xt[64 * 136];
    __shared__ ushort_t BlsT[128 * 40];
    __shared__ ushort_t ClsT[128 * 40];
    __shared__ ushort_t Gls[128 * 136];
    __shared__ ushort_t Spt[64 * 40];
    __shared__ float cumls[QCH];
    __shared__ float dtls[QCH];
    const int bid = blockIdx.x;
    const int c = bid & (NC - 1);
    const int hh = (bid / NC) & (NH - 1);
    const int b = bid / (NC * NH);
    const int bh = bid >> 4;           // = b*NH + hh  (NC == 16)
    const int m0 = b * T_ + c * QCH;
    const int tid = threadIdx.x;

    if (tid < QCH) {
        cumls[tid] = cum[(m0 + tid) * NH + hh];
        dtls[tid] = dtp[(m0 + tid) * NH + hh];
    }
    {
        const int p = tid & 63;
        const int s0 = tid >> 6;
#pragma unroll
        for (int pass = 0; pass < 32; ++pass) {
            const int s = s0 + pass * 4;
            Xt[p * 136 + s] = f2b(hbc[(m0 + s) * CONVDIM + hh * 64 + p]);
        }
    }
    for (int e = tid; e < QCH * 16; e += 256) {
        const int n = e & 15, s = e >> 4;
        BlsT[s * 40 + n] = f2b(hbc[(m0 + s) * CONVDIM + DINNER + n]);
        BlsT[s * 40 + 16 + n] = 0;
        ClsT[s * 40 + n] = f2b(hbc[(m0 + s) * CONVDIM + DINNER + NSTATE + n]);
        ClsT[s * 40 + 16 + n] = 0;
    }
    // per-block prefix scan over earlier chunks (replaces k_state_scan)
    {
        float4 S; S.x = 0.f; S.y = 0.f; S.z = 0.f; S.w = 0.f;
        for (int cc = 0; cc < c; ++cc) {
            const float d = dec[bh * NC + cc];
            const float4 z = *(const float4*)(zbuf + (bh * NC + cc) * 1024 + tid * 4);
            S.x = S.x * d + z.x; S.y = S.y * d + z.y;
            S.z = S.z * d + z.z; S.w = S.w * d + z.w;
        }
        // idx = p*16+n over [tid*4, tid*4+3]: p = tid>>2, n = (tid&3)*4
        const int p = tid >> 2, n = (tid & 3) * 4;
        Spt[p * 40 + n]     = f2b(S.x);
        Spt[p * 40 + n + 1] = f2b(S.y);
        Spt[p * 40 + n + 2] = f2b(S.z);
        Spt[p * 40 + n + 3] = f2b(S.w);
        Spt[p * 40 + 16 + n]     = 0;
        Spt[p * 40 + 16 + n + 1] = 0;
        Spt[p * 40 + 16 + n + 2] = 0;
        Spt[p * 40 + 16 + n + 3] = 0;
    }
    __syncthreads();

    const int lane = tid & 63, w = tid >> 6;
    const int wrow = w * 32;
    const int r16 = lane & 15, q8 = (lane >> 4) * 8, q4 = (lane >> 4) * 4;
    const float Dh = Dvec[l * NH + hh];

    bf8 cfr[2];
#pragma unroll
    for (int i = 0; i < 2; ++i)
        cfr[i] = *(const bf8*)&ClsT[(wrow + i * 16 + r16) * 40 + q8];

    float cumt[8], et[8];
#pragma unroll
    for (int i = 0; i < 2; ++i)
#pragma unroll
        for (int r = 0; r < 4; ++r) {
            const int t = wrow + i * 16 + q4 + r;
            cumt[i * 4 + r] = cumls[t];
            et[i * 4 + r] = __expf(cumls[t]);
        }

    f4v acc[2][4];
#pragma unroll
    for (int j = 0; j < 4; ++j) {
        const bf8 sf = *(const bf8*)&Spt[(j * 16 + r16) * 40 + q8];
#pragma unroll
        for (int i = 0; i < 2; ++i) {
            f4v z = (f4v)0.f;
            z = __builtin_amdgcn_mfma_f32_16x16x32_bf16(cfr[i], sf, z, 0, 0, 0);
#pragma unroll
            for (int r = 0; r < 4; ++r) {
                const int t = wrow + i * 16 + q4 + r;
                const int p = j * 16 + r16;
                acc[i][j][r] = z[r] * et[i * 4 + r] + Dh * b2f(Xt[p * 136 + t]);
            }
        }
    }

#pragma unroll
    for (int ts = 0; ts < 8; ++ts) {
        const bf8 bf = *(const bf8*)&BlsT[(ts * 16 + r16) * 40 + q8];
        const int s = ts * 16 + r16;
        const float cs = cumls[s];
        const float ds = dtls[s];
#pragma unroll
        for (int i = 0; i < 2; ++i) {
            f4v g = (f4v)0.f;
            g = __builtin_amdgcn_mfma_f32_16x16x32_bf16(cfr[i], bf, g, 0, 0, 0);
#pragma unroll
            for (int r = 0; r < 4; ++r) {
                const int t = wrow + i * 16 + q4 + r;
                const float val = (s <= t) ? __expf(cumt[i * 4 + r] - cs) * ds * g[r] : 0.f;
                Gls[t * 136 + s] = f2b(val);
            }
        }
    }
    __syncthreads();

#pragma unroll
    for (int kc = 0; kc < 128; kc += 32) {
        bf8 af[2];
#pragma unroll
        for (int i = 0; i < 2; ++i)
            af[i] = *(const bf8*)&Gls[(wrow + i * 16 + r16) * 136 + kc + q8];
#pragma unroll
        for (int j = 0; j < 4; ++j) {
            const bf8 xf = *(const bf8*)&Xt[(j * 16 + r16) * 136 + kc + q8];
#pragma unroll
            for (int i = 0; i < 2; ++i)
                acc[i][j] = __builtin_amdgcn_mfma_f32_16x16x32_bf16(af[i], xf, acc[i][j], 0, 0, 0);
        }
    }

#pragma unroll
    for (int i = 0; i < 2; ++i)
#pragma unroll
        for (int r = 0; r < 4; ++r) {
            const int t = wrow + i * 16 + q4 + r;
#pragma unroll
            for (int j = 0; j < 4; ++j) {
                const int p = j * 16 + r16;
                ybuf[(m0 + t) * DINNER + hh * 64 + p] = acc[i][j][r];
            }
        }
}

// ===== final rmsnorm + partial mean-pool (proven) =====
__global__ __launch_bounds__(256) void k_finalnorm_pool(
    const float* __restrict__ h, const float* __restrict__ nfw,
    float* __restrict__ part)
{
    __shared__ float ht[2048];
    __shared__ float red[256];
    __shared__ float rstd[16];
    __shared__ float padd[256];
    const int tile = blockIdx.x & 127;
    const int b = blockIdx.x >> 7;
    const int m0 = b * T_ + tile * 16;
    const int tid = threadIdx.x;
    for (int e = tid; e < 2048; e += 256) ht[e] = h[m0 * DM + e];
    __syncthreads();
    {
        const int tg = tid >> 4, j0 = tid & 15;
        float p = 0.f;
#pragma unroll
        for (int k = 0; k < 8; ++k) { const float v = ht[tg * 128 + j0 + 16 * k]; p += v * v; }
        red[tid] = p;
    }
    __syncthreads();
    if (tid < 16) {
        float s = 0.f;
#pragma unroll
        for (int q = 0; q < 16; ++q) s += red[tid * 16 + q];
        rstd[tid] = rsqrtf(s * (1.f / 128.f) + EPSF);
    }
    __syncthreads();
    const int d = tid & 127, half = tid >> 7;
    float ps = 0.f;
#pragma unroll
    for (int i0 = 0; i0 < 8; ++i0) { const int i = half + 2 * i0; ps += ht[i * 128 + d] * rstd[i]; }
    padd[tid] = ps;
    __syncthreads();
    if (tid < 128) part[(b * 128 + tile) * 128 + tid] = (padd[tid] + padd[128 + tid]) * nfw[tid];
}

// ===== pooled reduce + head GEMM (proven) =====
__global__ __launch_bounds__(256) void k_head(
    const float* __restrict__ part, const float* __restrict__ ow,
    const float* __restrict__ ob, float* __restrict__ out)
{
    __shared__ float pooled[128];
    const int b = blockIdx.x;
    const int tid = threadIdx.x;
    if (tid < 128) {
        float s = 0.f;
        for (int tile = 0; tile < 128; ++tile) s += part[(b * 128 + tile) * 128 + tid];
        pooled[tid] = s * (1.f / (float)T_);
    }
    __syncthreads();
    for (int o = tid; o < DIMX; o += 256) {
        float acc = ob[o];
#pragma unroll 4
        for (int d = 0; d < 128; ++d) acc += pooled[d] * ow[d * DIMX + o];
        out[b * DIMX + o] = acc;
    }
}

extern "C" void kernel_launch(void* const* d_in, const int* in_sizes, int n_in,
                              void* d_out, int out_size, void* d_ws, size_t ws_size,
                              hipStream_t stream)
{
    const float* x         = (const float*)d_in[0];
    const float* in_w      = (const float*)d_in[1];
    const float* in_b      = (const float*)d_in[2];
    const float* norm_w    = (const float*)d_in[3];
    const float* inproj_w  = (const float*)d_in[4];
    const float* conv_w    = (const float*)d_in[5];
    const float* conv_b    = (const float*)d_in[6];
    const float* A_log     = (const float*)d_in[7];
    const float* Dvec      = (const float*)d_in[8];
    const float* dt_bias   = (const float*)d_in[9];
    const float* gnorm_w   = (const float*)d_in[10];
    const float* outproj_w = (const float*)d_in[11];
    const float* normf_w   = (const float*)d_in[12];
    const float* out_w     = (const float*)d_in[13];
    const float* out_b     = (const float*)d_in[14];

    float* ws    = (float*)d_ws;
    float* h     = ws + OFF_H;
    float* proj  = ws + OFF_PROJ;
    float* hbc   = ws + OFF_HBC;
    float* ybuf  = ws + OFF_Y;
    float* dtp   = ws + OFF_DTP;
    float* cumb  = ws + OFF_CUM;
    float* zbuf  = ws + OFF_Z;
    float* dec   = ws + OFF_DEC;
    float* part  = ws + OFF_PART;
    ushort_t* bf_scr = (ushort_t*)(ws + OFF_BF);
    ushort_t* wt_in  = (ushort_t*)(ws + OFF_WTIN);
    ushort_t* wt_inp = (ushort_t*)(ws + OFF_WTINP);
    ushort_t* wt_out = (ushort_t*)(ws + OFF_WTOUT);

    k_wt_all<<<68, 256, 0, stream>>>(in_w, inproj_w, outproj_w, wt_in, wt_inp, wt_out);

    k_gemm<512, 128, 0, 1, false><<<dim3(MTOK / 64, 2), 256, 0, stream>>>(x, wt_in, in_b, h);

    for (int l = 0; l < LLAYERS; ++l) {
        k_rmsnorm<<<MTOK / 4, 256, 0, stream>>>(h, norm_w + l * DM, bf_scr);
        k_gemm<128, PROJ, PROJ, 0, true><<<dim3(MTOK / 64, 9), 256, 0, stream>>>(
            bf_scr, wt_inp + l * 576 * 128, nullptr, proj);
        k_convdt<<<(MTOK * CONVDIM) / 256 + B_ * NH * NC, 256, 0, stream>>>(
            proj, conv_w, conv_b, A_log, dt_bias, hbc, dtp, cumb, l);
        k_ssd_state<<<B_ * NH * NC, 256, 0, stream>>>(hbc, dtp, cumb, zbuf, dec);
        k_ssd_y<<<B_ * NH * NC, 256, 0, stream>>>(hbc, dtp, cumb, zbuf, dec, Dvec, ybuf, l);
        k_gnorm<<<MTOK / 4, 256, 0, stream>>>(ybuf, proj, gnorm_w + l * DINNER, bf_scr);
        k_gemm<256, 128, 0, 2, true><<<dim3(MTOK / 64, 2), 256, 0, stream>>>(
            bf_scr, wt_out + l * 128 * 256, nullptr, h);
    }

    k_finalnorm_pool<<<B_ * (T_ / 16), 256, 0, stream>>>(h, normf_w, part);
    k_head<<<B_, 256, 0, stream>>>(part, out_w, out_b, (float*)d_out);
}

// Round 3
// 299.263 us; speedup vs baseline: 2.2760x; 1.0005x over previous
//
#include <hip/hip_runtime.h>
#include <math.h>

typedef unsigned short ushort_t;
typedef unsigned int uint_t;

// Problem constants
#define B_      8
#define T_      2048
#define DIMX    512
#define DM      128
#define DINNER  256
#define NSTATE  16
#define HDIM    64
#define NH      4
#define CONVDIM 288
#define PROJ    548
#define KCONV   4
#define LLAYERS 2
#define QCH     128
#define NC      (T_/QCH)
#define EPSF    1e-5f
#define MTOK    (B_*T_)

// ---- workspace layout (float offsets) — identical to round-8 passing build ----
#define OFF_H      0u
#define OFF_PROJ   2097152u
#define OFF_HBC    11075584u
#define OFF_Y      15794176u
#define OFF_DTP    19988480u
#define OFF_CUM    20054016u
#define OFF_Z      20119552u
#define OFF_SPREV  20643840u
#define OFF_DEC    21168128u
#define OFF_PART   21168640u
#define OFF_BF     21299712u
#define OFF_WTIN   23396864u
#define OFF_WTINP  23429632u
#define OFF_WTOUT  23503360u

__device__ __forceinline__ ushort_t f2b(float f) {
    uint_t u = __builtin_bit_cast(uint_t, f);
    return (ushort_t)((u + 0x7FFFu + ((u >> 16) & 1u)) >> 16);
}
__device__ __forceinline__ float b2f(ushort_t b) {
    uint_t u = ((uint_t)b) << 16;
    return __builtin_bit_cast(float, u);
}

typedef short bf8 __attribute__((ext_vector_type(8)));
typedef float f4v __attribute__((ext_vector_type(4)));

// ===== all weight transposes in ONE kernel (proven r8) =====
__global__ __launch_bounds__(256) void k_wt_all(
    const float* __restrict__ in_w, const float* __restrict__ inproj_w,
    const float* __restrict__ outproj_w,
    ushort_t* __restrict__ wt_in, ushort_t* __restrict__ wt_inp,
    ushort_t* __restrict__ wt_out)
{
    __shared__ float tile[64][65];
    int idx = blockIdx.x;
    const float* W; ushort_t* Wt; int K, N, k0, n0;
    if (idx < 16) {
        W = in_w; Wt = wt_in; K = 512; N = 128;
        k0 = (idx & 7) * 64; n0 = (idx >> 3) * 64;
    } else if (idx < 52) {
        int r = idx - 16; int l = r / 18; r -= l * 18;
        W = inproj_w + l * 128 * PROJ; Wt = wt_inp + l * 576 * 128; K = 128; N = PROJ;
        k0 = (r & 1) * 64; n0 = (r >> 1) * 64;
    } else {
        int r = idx - 52; int l = r / 8; r -= l * 8;
        W = outproj_w + l * 256 * 128; Wt = wt_out + l * 128 * 256; K = 256; N = 128;
        k0 = (r & 3) * 64; n0 = (r >> 2) * 64;
    }
    const int tid = threadIdx.x;
#pragma unroll
    for (int it = 0; it < 16; ++it) {
        const int e = it * 256 + tid;
        const int kk = e >> 6, nn = e & 63;
        tile[kk][nn] = (n0 + nn < N) ? W[(k0 + kk) * N + (n0 + nn)] : 0.f;
    }
    __syncthreads();
#pragma unroll
    for (int it = 0; it < 16; ++it) {
        const int e = it * 256 + tid;
        const int nn = e >> 6, kk = e & 63;
        Wt[(n0 + nn) * K + k0 + kk] = f2b(tile[kk][nn]);
    }
}

// ===== MFMA GEMM template (proven r8) — used for the input projection =====
// EPI: 0 = plain, 1 = +bias(aux[col]), 2 = += C in place (residual)
template<int KTOT, int LDC, int NGUARD, int EPI, bool ABF16>
__global__ __launch_bounds__(256) void k_gemm(
    const void* __restrict__ Ap, const ushort_t* __restrict__ Bt,
    const float* __restrict__ aux, float* __restrict__ C)
{
    __shared__ ushort_t Als[64 * 136];
    __shared__ ushort_t Bls[64 * 136];
    const int m0 = blockIdx.x * 64, n0 = blockIdx.y * 64;
    const int tid = threadIdx.x;
    const int lane = tid & 63, w = tid >> 6;
    const int wm = (w >> 1) * 32, wn = (w & 1) * 32;
    const int r16 = lane & 15, q8 = (lane >> 4) * 8;

    f4v acc[2][2];
#pragma unroll
    for (int i = 0; i < 2; ++i)
#pragma unroll
        for (int j = 0; j < 2; ++j) acc[i][j] = (f4v)0.f;

    for (int kc = 0; kc < KTOT; kc += 128) {
        if constexpr (ABF16) {
            const ushort_t* A = (const ushort_t*)Ap;
#pragma unroll
            for (int i = 0; i < 4; ++i) {
                const int e = i * 2048 + tid * 8;
                const int r = e >> 7, c = e & 127;
                *(uint4*)&Als[r * 136 + c] = *(const uint4*)&A[(m0 + r) * KTOT + kc + c];
            }
        } else {
            const float* A = (const float*)Ap;
#pragma unroll
            for (int i = 0; i < 4; ++i) {
                const int e = i * 2048 + tid * 8;
                const int r = e >> 7, c = e & 127;
                const float4 f0 = *(const float4*)&A[(m0 + r) * KTOT + kc + c];
                const float4 f1 = *(const float4*)&A[(m0 + r) * KTOT + kc + c + 4];
                uint4 pk;
                pk.x = (uint_t)f2b(f0.x) | ((uint_t)f2b(f0.y) << 16);
                pk.y = (uint_t)f2b(f0.z) | ((uint_t)f2b(f0.w) << 16);
                pk.z = (uint_t)f2b(f1.x) | ((uint_t)f2b(f1.y) << 16);
                pk.w = (uint_t)f2b(f1.z) | ((uint_t)f2b(f1.w) << 16);
                *(uint4*)&Als[r * 136 + c] = pk;
            }
        }
#pragma unroll
        for (int i = 0; i < 4; ++i) {
            const int e = i * 2048 + tid * 8;
            const int r = e >> 7, c = e & 127;
            *(uint4*)&Bls[r * 136 + c] = *(const uint4*)&Bt[(n0 + r) * KTOT + kc + c];
        }
        __syncthreads();
#pragma unroll
        for (int kk = 0; kk < 128; kk += 32) {
            const bf8 a0 = *(const bf8*)&Als[(wm + r16) * 136 + kk + q8];
            const bf8 a1 = *(const bf8*)&Als[(wm + 16 + r16) * 136 + kk + q8];
            const bf8 b0 = *(const bf8*)&Bls[(wn + r16) * 136 + kk + q8];
            const bf8 b1 = *(const bf8*)&Bls[(wn + 16 + r16) * 136 + kk + q8];
            acc[0][0] = __builtin_amdgcn_mfma_f32_16x16x32_bf16(a0, b0, acc[0][0], 0, 0, 0);
            acc[0][1] = __builtin_amdgcn_mfma_f32_16x16x32_bf16(a0, b1, acc[0][1], 0, 0, 0);
            acc[1][0] = __builtin_amdgcn_mfma_f32_16x16x32_bf16(a1, b0, acc[1][0], 0, 0, 0);
            acc[1][1] = __builtin_amdgcn_mfma_f32_16x16x32_bf16(a1, b1, acc[1][1], 0, 0, 0);
        }
        __syncthreads();
    }
    const int q4 = (lane >> 4) * 4;
#pragma unroll
    for (int i = 0; i < 2; ++i)
#pragma unroll
        for (int j = 0; j < 2; ++j)
#pragma unroll
            for (int r = 0; r < 4; ++r) {
                const int grow = m0 + wm + i * 16 + q4 + r;
                const int gcol = n0 + wn + j * 16 + r16;
                if (NGUARD == 0 || gcol < NGUARD) {
                    float v = acc[i][j][r];
                    if (EPI == 1) v += aux[gcol];
                    if (EPI == 2) v += C[grow * LDC + gcol];
                    C[grow * LDC + gcol] = v;
                }
            }
}

// ===== NEW: inproj GEMM with inline RMSNorm on A (replaces k_rmsnorm + gemm) =====
// A = h (fp32, MTOK x 128); K = 128 = single tile. Row r's 128 cols are staged
// by the 16 consecutive, 16-aligned lanes r%16*... -> sumsq via 4-step
// shfl_xor tree (<=16), then scale by rsqrt and norm_w and pack bf16 into Als.
// Per-element math identical to old k_rmsnorm (same rsqrtf formula); only the
// reduction tree order differs (~1 ulp on the fp32 sum).
__global__ __launch_bounds__(256) void k_gemm_rms(
    const float* __restrict__ h, const float* __restrict__ nw,
    const ushort_t* __restrict__ Bt, float* __restrict__ C)
{
    __shared__ ushort_t Als[64 * 136];
    __shared__ ushort_t Bls[64 * 136];
    const int m0 = blockIdx.x * 64, n0 = blockIdx.y * 64;
    const int tid = threadIdx.x;
    const int lane = tid & 63, w = tid >> 6;
    const int wm = (w >> 1) * 32, wn = (w & 1) * 32;
    const int r16 = lane & 15, q8 = (lane >> 4) * 8;

    // A staging + inline rmsnorm: 4 passes x 2048 elems; 16 rows/pass,
    // 16 lanes per row (aligned 16-groups -> shfl_xor stays in-row).
#pragma unroll
    for (int i = 0; i < 4; ++i) {
        const int e = i * 2048 + tid * 8;
        const int r = e >> 7, c = e & 127;
        const float4 f0 = *(const float4*)&h[(m0 + r) * 128 + c];
        const float4 f1 = *(const float4*)&h[(m0 + r) * 128 + c + 4];
        float ss = f0.x * f0.x + f0.y * f0.y + f0.z * f0.z + f0.w * f0.w
                 + f1.x * f1.x + f1.y * f1.y + f1.z * f1.z + f1.w * f1.w;
#pragma unroll
        for (int off = 1; off < 16; off <<= 1) ss += __shfl_xor(ss, off);
        const float rs = rsqrtf(ss * (1.f / 128.f) + EPSF);
        const float4 w0 = *(const float4*)&nw[c];
        const float4 w1 = *(const float4*)&nw[c + 4];
        uint4 pk;
        pk.x = (uint_t)f2b(f0.x * rs * w0.x) | ((uint_t)f2b(f0.y * rs * w0.y) << 16);
        pk.y = (uint_t)f2b(f0.z * rs * w0.z) | ((uint_t)f2b(f0.w * rs * w0.w) << 16);
        pk.z = (uint_t)f2b(f1.x * rs * w1.x) | ((uint_t)f2b(f1.y * rs * w1.y) << 16);
        pk.w = (uint_t)f2b(f1.z * rs * w1.z) | ((uint_t)f2b(f1.w * rs * w1.w) << 16);
        *(uint4*)&Als[r * 136 + c] = pk;
    }
#pragma unroll
    for (int i = 0; i < 4; ++i) {
        const int e = i * 2048 + tid * 8;
        const int r = e >> 7, c = e & 127;
        *(uint4*)&Bls[r * 136 + c] = *(const uint4*)&Bt[(n0 + r) * 128 + c];
    }
    __syncthreads();

    f4v acc[2][2];
#pragma unroll
    for (int i = 0; i < 2; ++i)
#pragma unroll
        for (int j = 0; j < 2; ++j) acc[i][j] = (f4v)0.f;
#pragma unroll
    for (int kk = 0; kk < 128; kk += 32) {
        const bf8 a0 = *(const bf8*)&Als[(wm + r16) * 136 + kk + q8];
        const bf8 a1 = *(const bf8*)&Als[(wm + 16 + r16) * 136 + kk + q8];
        const bf8 b0 = *(const bf8*)&Bls[(wn + r16) * 136 + kk + q8];
        const bf8 b1 = *(const bf8*)&Bls[(wn + 16 + r16) * 136 + kk + q8];
        acc[0][0] = __builtin_amdgcn_mfma_f32_16x16x32_bf16(a0, b0, acc[0][0], 0, 0, 0);
        acc[0][1] = __builtin_amdgcn_mfma_f32_16x16x32_bf16(a0, b1, acc[0][1], 0, 0, 0);
        acc[1][0] = __builtin_amdgcn_mfma_f32_16x16x32_bf16(a1, b0, acc[1][0], 0, 0, 0);
        acc[1][1] = __builtin_amdgcn_mfma_f32_16x16x32_bf16(a1, b1, acc[1][1], 0, 0, 0);
    }

    const int q4 = (lane >> 4) * 4;
#pragma unroll
    for (int i = 0; i < 2; ++i)
#pragma unroll
        for (int j = 0; j < 2; ++j)
#pragma unroll
            for (int r = 0; r < 4; ++r) {
                const int grow = m0 + wm + i * 16 + q4 + r;
                const int gcol = n0 + wn + j * 16 + r16;
                if (gcol < PROJ) C[grow * PROJ + gcol] = acc[i][j][r];
            }
}

// ===== NEW: outproj GEMM with inline gated-RMSNorm on A (replaces k_gnorm + gemm) =====
// A row r = gnorm(ybuf[row], silu(gate[row])) over 256 cols; whole A staged at
// once (rows need full-width sumsq before packing). 8 passes x 8 rows, 32
// lanes per row (aligned 32-groups). Als stride 264 (same bank profile as 136).
__global__ __launch_bounds__(256) void k_gemm_gn(
    const float* __restrict__ y, const float* __restrict__ proj,
    const float* __restrict__ gw, const ushort_t* __restrict__ Bt,
    float* __restrict__ C)
{
    __shared__ ushort_t Als[64 * 264];
    __shared__ ushort_t Bls[64 * 136];
    const int m0 = blockIdx.x * 64, n0 = blockIdx.y * 64;
    const int tid = threadIdx.x;
    const int lane = tid & 63, w = tid >> 6;
    const int wm = (w >> 1) * 32, wn = (w & 1) * 32;
    const int r16 = lane & 15, q8 = (lane >> 4) * 8;

    // A staging + inline gated rmsnorm
#pragma unroll
    for (int i = 0; i < 8; ++i) {
        const int e = i * 2048 + tid * 8;
        const int r = e >> 8, c = e & 255;
        const float4 y0 = *(const float4*)&y[(m0 + r) * 256 + c];
        const float4 y1 = *(const float4*)&y[(m0 + r) * 256 + c + 4];
        const float4 g0 = *(const float4*)&proj[(m0 + r) * PROJ + c];
        const float4 g1 = *(const float4*)&proj[(m0 + r) * PROJ + c + 4];
        float v0 = y0.x * (g0.x / (1.f + __expf(-g0.x)));
        float v1 = y0.y * (g0.y / (1.f + __expf(-g0.y)));
        float v2 = y0.z * (g0.z / (1.f + __expf(-g0.z)));
        float v3 = y0.w * (g0.w / (1.f + __expf(-g0.w)));
        float v4 = y1.x * (g1.x / (1.f + __expf(-g1.x)));
        float v5 = y1.y * (g1.y / (1.f + __expf(-g1.y)));
        float v6 = y1.z * (g1.z / (1.f + __expf(-g1.z)));
        float v7 = y1.w * (g1.w / (1.f + __expf(-g1.w)));
        float ss = v0 * v0 + v1 * v1 + v2 * v2 + v3 * v3
                 + v4 * v4 + v5 * v5 + v6 * v6 + v7 * v7;
#pragma unroll
        for (int off = 1; off < 32; off <<= 1) ss += __shfl_xor(ss, off);
        const float rs = rsqrtf(ss * (1.f / 256.f) + EPSF);
        const float4 w0 = *(const float4*)&gw[c];
        const float4 w1 = *(const float4*)&gw[c + 4];
        uint4 pk;
        pk.x = (uint_t)f2b(v0 * rs * w0.x) | ((uint_t)f2b(v1 * rs * w0.y) << 16);
        pk.y = (uint_t)f2b(v2 * rs * w0.z) | ((uint_t)f2b(v3 * rs * w0.w) << 16);
        pk.z = (uint_t)f2b(v4 * rs * w1.x) | ((uint_t)f2b(v5 * rs * w1.y) << 16);
        pk.w = (uint_t)f2b(v6 * rs * w1.z) | ((uint_t)f2b(v7 * rs * w1.w) << 16);
        *(uint4*)&Als[r * 264 + c] = pk;
    }

    f4v acc[2][2];
#pragma unroll
    for (int i = 0; i < 2; ++i)
#pragma unroll
        for (int j = 0; j < 2; ++j) acc[i][j] = (f4v)0.f;

    for (int kc = 0; kc < 256; kc += 128) {
#pragma unroll
        for (int i = 0; i < 4; ++i) {
            const int e = i * 2048 + tid * 8;
            const int r = e >> 7, c = e & 127;
            *(uint4*)&Bls[r * 136 + c] = *(const uint4*)&Bt[(n0 + r) * 256 + kc + c];
        }
        __syncthreads();
#pragma unroll
        for (int kk = 0; kk < 128; kk += 32) {
            const bf8 a0 = *(const bf8*)&Als[(wm + r16) * 264 + kc + kk + q8];
            const bf8 a1 = *(const bf8*)&Als[(wm + 16 + r16) * 264 + kc + kk + q8];
            const bf8 b0 = *(const bf8*)&Bls[(wn + r16) * 136 + kk + q8];
            const bf8 b1 = *(const bf8*)&Bls[(wn + 16 + r16) * 136 + kk + q8];
            acc[0][0] = __builtin_amdgcn_mfma_f32_16x16x32_bf16(a0, b0, acc[0][0], 0, 0, 0);
            acc[0][1] = __builtin_amdgcn_mfma_f32_16x16x32_bf16(a0, b1, acc[0][1], 0, 0, 0);
            acc[1][0] = __builtin_amdgcn_mfma_f32_16x16x32_bf16(a1, b0, acc[1][0], 0, 0, 0);
            acc[1][1] = __builtin_amdgcn_mfma_f32_16x16x32_bf16(a1, b1, acc[1][1], 0, 0, 0);
        }
        __syncthreads();
    }

    const int q4 = (lane >> 4) * 4;
#pragma unroll
    for (int i = 0; i < 2; ++i)
#pragma unroll
        for (int j = 0; j < 2; ++j)
#pragma unroll
            for (int r = 0; r < 4; ++r) {
                const int grow = m0 + wm + i * 16 + q4 + r;
                const int gcol = n0 + wn + j * 16 + r16;
                C[grow * 128 + gcol] += acc[i][j][r];
            }
}

// ===== conv + dtprep merged (proven) =====
__global__ __launch_bounds__(256) void k_convdt(
    const float* __restrict__ proj, const float* __restrict__ cw,
    const float* __restrict__ cb, const float* __restrict__ A_log,
    const float* __restrict__ dt_bias, float* __restrict__ hbc,
    float* __restrict__ dtp, float* __restrict__ cum, int l)
{
    __shared__ float sc[128];
    const int bid = blockIdx.x;
    const int tid = threadIdx.x;
    if (bid < (MTOK * CONVDIM) / 256) {
        const int e = bid * 256 + tid;
        const int m = e / CONVDIM;
        const int cch = e - m * CONVDIM;
        const int b = m >> 11;
        const int t = m & (T_ - 1);
        const float* wp = cw + (l * CONVDIM + cch) * KCONV;
        float acc = cb[l * CONVDIM + cch];
#pragma unroll
        for (int k = 0; k < KCONV; ++k) {
            const int tt = t - (KCONV - 1) + k;
            if (tt >= 0) acc += proj[(b * T_ + tt) * PROJ + DINNER + cch] * wp[k];
        }
        hbc[m * CONVDIM + cch] = acc / (1.f + __expf(-acc));
    } else {
        const int bid2 = bid - (MTOK * CONVDIM) / 256;
        const int c = bid2 & (NC - 1);
        const int hh = (bid2 / NC) & (NH - 1);
        const int b = bid2 / (NC * NH);
        const int t = tid;
        float dtv = 0.f;
        if (t < 128) {
            const int m = b * T_ + c * QCH + t;
            const float Ah = -expf(A_log[l * NH + hh]);
            const float raw = proj[m * PROJ + DINNER + CONVDIM + hh] + dt_bias[l * NH + hh];
            dtv = (raw > 20.f) ? raw : log1pf(expf(raw));
            sc[t] = dtv * Ah;
        }
        __syncthreads();
        for (int off = 1; off < 128; off <<= 1) {
            const float v = (t >= off && t < 128) ? sc[t - off] : 0.f;
            __syncthreads();
            if (t < 128) sc[t] += v;
            __syncthreads();
        }
        if (t < 128) {
            const int m = b * T_ + c * QCH + t;
            dtp[m * NH + hh] = dtv;
            cum[m * NH + hh] = sc[t];
        }
    }
}

// ===== SSD chunk state (proven r8) =====
__global__ __launch_bounds__(256) void k_ssd_state(
    const float* __restrict__ hbc, const float* __restrict__ dtp,
    const float* __restrict__ cum, float* __restrict__ zbuf,
    float* __restrict__ dec)
{
    __shared__ ushort_t Xt[64 * 136];
    __shared__ ushort_t wB[16 * 136];
    __shared__ float cumls[QCH];
    __shared__ float dtls[QCH];
    const int bid = blockIdx.x;
    const int c = bid & (NC - 1);
    const int hh = (bid / NC) & (NH - 1);
    const int b = bid / (NC * NH);
    const int m0 = b * T_ + c * QCH;
    const int tid = threadIdx.x;

    if (tid < QCH) {
        cumls[tid] = cum[(m0 + tid) * NH + hh];
        dtls[tid] = dtp[(m0 + tid) * NH + hh];
    }
    __syncthreads();
    const float clast = cumls[QCH - 1];
    {
        const int p = tid & 63;
        const int s0 = tid >> 6;
#pragma unroll
        for (int pass = 0; pass < 32; ++pass) {
            const int s = s0 + pass * 4;
            Xt[p * 136 + s] = f2b(hbc[(m0 + s) * CONVDIM + hh * 64 + p]);
        }
    }
    for (int e = tid; e < QCH * 16; e += 256) {
        const int n = e & 15, s = e >> 4;
        const float w = __expf(clast - cumls[s]) * dtls[s];
        wB[n * 136 + s] = f2b(w * hbc[(m0 + s) * CONVDIM + DINNER + n]);
    }
    __syncthreads();

    const int lane = tid & 63, w = tid >> 6;
    const int r16 = lane & 15, q8 = (lane >> 4) * 8, q4 = (lane >> 4) * 4;
    f4v acc = (f4v)0.f;
#pragma unroll
    for (int kc = 0; kc < 128; kc += 32) {
        const bf8 a = *(const bf8*)&Xt[(w * 16 + r16) * 136 + kc + q8];
        const bf8 bb = *(const bf8*)&wB[r16 * 136 + kc + q8];
        acc = __builtin_amdgcn_mfma_f32_16x16x32_bf16(a, bb, acc, 0, 0, 0);
    }
#pragma unroll
    for (int r = 0; r < 4; ++r) {
        const int p = w * 16 + q4 + r;
        zbuf[bid * 1024 + p * 16 + r16] = acc[r];
    }
    if (tid == 0) dec[bid] = __expf(clast);
}

// ===== fused SSD y + per-block inter-chunk scan (proven r2) =====
__global__ __launch_bounds__(256) void k_ssd_y(
    const float* __restrict__ hbc, const float* __restrict__ dtp,
    const float* __restrict__ cum, const float* __restrict__ zbuf,
    const float* __restrict__ dec, const float* __restrict__ Dvec,
    float* __restrict__ ybuf, int l)
{
    __shared__ ushort_t Xt[64 * 136];
    __shared__ ushort_t BlsT[128 * 40];
    __shared__ ushort_t ClsT[128 * 40];
    __shared__ ushort_t Gls[128 * 136];
    __shared__ ushort_t Spt[64 * 40];
    __shared__ float cumls[QCH];
    __shared__ float dtls[QCH];
    const int bid = blockIdx.x;
    const int c = bid & (NC - 1);
    const int hh = (bid / NC) & (NH - 1);
    const int b = bid / (NC * NH);
    const int bh = bid >> 4;           // = b*NH + hh  (NC == 16)
    const int m0 = b * T_ + c * QCH;
    const int tid = threadIdx.x;

    if (tid < QCH) {
        cumls[tid] = cum[(m0 + tid) * NH + hh];
        dtls[tid] = dtp[(m0 + tid) * NH + hh];
    }
    {
        const int p = tid & 63;
        const int s0 = tid >> 6;
#pragma unroll
        for (int pass = 0; pass < 32; ++pass) {
            const int s = s0 + pass * 4;
            Xt[p * 136 + s] = f2b(hbc[(m0 + s) * CONVDIM + hh * 64 + p]);
        }
    }
    for (int e = tid; e < QCH * 16; e += 256) {
        const int n = e & 15, s = e >> 4;
        BlsT[s * 40 + n] = f2b(hbc[(m0 + s) * CONVDIM + DINNER + n]);
        BlsT[s * 40 + 16 + n] = 0;
        ClsT[s * 40 + n] = f2b(hbc[(m0 + s) * CONVDIM + DINNER + NSTATE + n]);
        ClsT[s * 40 + 16 + n] = 0;
    }
    // per-block prefix scan over earlier chunks (replaces k_state_scan)
    {
        float4 S; S.x = 0.f; S.y = 0.f; S.z = 0.f; S.w = 0.f;
        for (int cc = 0; cc < c; ++cc) {
            const float d = dec[bh * NC + cc];
            const float4 z = *(const float4*)(zbuf + (bh * NC + cc) * 1024 + tid * 4);
            S.x = S.x * d + z.x; S.y = S.y * d + z.y;
            S.z = S.z * d + z.z; S.w = S.w * d + z.w;
        }
        const int p = tid >> 2, n = (tid & 3) * 4;
        Spt[p * 40 + n]     = f2b(S.x);
        Spt[p * 40 + n + 1] = f2b(S.y);
        Spt[p * 40 + n + 2] = f2b(S.z);
        Spt[p * 40 + n + 3] = f2b(S.w);
        Spt[p * 40 + 16 + n]     = 0;
        Spt[p * 40 + 16 + n + 1] = 0;
        Spt[p * 40 + 16 + n + 2] = 0;
        Spt[p * 40 + 16 + n + 3] = 0;
    }
    __syncthreads();

    const int lane = tid & 63, w = tid >> 6;
    const int wrow = w * 32;
    const int r16 = lane & 15, q8 = (lane >> 4) * 8, q4 = (lane >> 4) * 4;
    const float Dh = Dvec[l * NH + hh];

    bf8 cfr[2];
#pragma unroll
    for (int i = 0; i < 2; ++i)
        cfr[i] = *(const bf8*)&ClsT[(wrow + i * 16 + r16) * 40 + q8];

    float cumt[8], et[8];
#pragma unroll
    for (int i = 0; i < 2; ++i)
#pragma unroll
        for (int r = 0; r < 4; ++r) {
            const int t = wrow + i * 16 + q4 + r;
            cumt[i * 4 + r] = cumls[t];
            et[i * 4 + r] = __expf(cumls[t]);
        }

    f4v acc[2][4];
#pragma unroll
    for (int j = 0; j < 4; ++j) {
        const bf8 sf = *(const bf8*)&Spt[(j * 16 + r16) * 40 + q8];
#pragma unroll
        for (int i = 0; i < 2; ++i) {
            f4v z = (f4v)0.f;
            z = __builtin_amdgcn_mfma_f32_16x16x32_bf16(cfr[i], sf, z, 0, 0, 0);
#pragma unroll
            for (int r = 0; r < 4; ++r) {
                const int t = wrow + i * 16 + q4 + r;
                const int p = j * 16 + r16;
                acc[i][j][r] = z[r] * et[i * 4 + r] + Dh * b2f(Xt[p * 136 + t]);
            }
        }
    }

#pragma unroll
    for (int ts = 0; ts < 8; ++ts) {
        const bf8 bf = *(const bf8*)&BlsT[(ts * 16 + r16) * 40 + q8];
        const int s = ts * 16 + r16;
        const float cs = cumls[s];
        const float ds = dtls[s];
#pragma unroll
        for (int i = 0; i < 2; ++i) {
            f4v g = (f4v)0.f;
            g = __builtin_amdgcn_mfma_f32_16x16x32_bf16(cfr[i], bf, g, 0, 0, 0);
#pragma unroll
            for (int r = 0; r < 4; ++r) {
                const int t = wrow + i * 16 + q4 + r;
                const float val = (s <= t) ? __expf(cumt[i * 4 + r] - cs) * ds * g[r] : 0.f;
                Gls[t * 136 + s] = f2b(val);
            }
        }
    }
    __syncthreads();

#pragma unroll
    for (int kc = 0; kc < 128; kc += 32) {
        bf8 af[2];
#pragma unroll
        for (int i = 0; i < 2; ++i)
            af[i] = *(const bf8*)&Gls[(wrow + i * 16 + r16) * 136 + kc + q8];
#pragma unroll
        for (int j = 0; j < 4; ++j) {
            const bf8 xf = *(const bf8*)&Xt[(j * 16 + r16) * 136 + kc + q8];
#pragma unroll
            for (int i = 0; i < 2; ++i)
                acc[i][j] = __builtin_amdgcn_mfma_f32_16x16x32_bf16(af[i], xf, acc[i][j], 0, 0, 0);
        }
    }

#pragma unroll
    for (int i = 0; i < 2; ++i)
#pragma unroll
        for (int r = 0; r < 4; ++r) {
            const int t = wrow + i * 16 + q4 + r;
#pragma unroll
            for (int j = 0; j < 4; ++j) {
                const int p = j * 16 + r16;
                ybuf[(m0 + t) * DINNER + hh * 64 + p] = acc[i][j][r];
            }
        }
}

// ===== final rmsnorm + partial mean-pool (proven) =====
__global__ __launch_bounds__(256) void k_finalnorm_pool(
    const float* __restrict__ h, const float* __restrict__ nfw,
    float* __restrict__ part)
{
    __shared__ float ht[2048];
    __shared__ float red[256];
    __shared__ float rstd[16];
    __shared__ float padd[256];
    const int tile = blockIdx.x & 127;
    const int b = blockIdx.x >> 7;
    const int m0 = b * T_ + tile * 16;
    const int tid = threadIdx.x;
    for (int e = tid; e < 2048; e += 256) ht[e] = h[m0 * DM + e];
    __syncthreads();
    {
        const int tg = tid >> 4, j0 = tid & 15;
        float p = 0.f;
#pragma unroll
        for (int k = 0; k < 8; ++k) { const float v = ht[tg * 128 + j0 + 16 * k]; p += v * v; }
        red[tid] = p;
    }
    __syncthreads();
    if (tid < 16) {
        float s = 0.f;
#pragma unroll
        for (int q = 0; q < 16; ++q) s += red[tid * 16 + q];
        rstd[tid] = rsqrtf(s * (1.f / 128.f) + EPSF);
    }
    __syncthreads();
    const int d = tid & 127, half = tid >> 7;
    float ps = 0.f;
#pragma unroll
    for (int i0 = 0; i0 < 8; ++i0) { const int i = half + 2 * i0; ps += ht[i * 128 + d] * rstd[i]; }
    padd[tid] = ps;
    __syncthreads();
    if (tid < 128) part[(b * 128 + tile) * 128 + tid] = (padd[tid] + padd[128 + tid]) * nfw[tid];
}

// ===== pooled reduce + head GEMM (proven) =====
__global__ __launch_bounds__(256) void k_head(
    const float* __restrict__ part, const float* __restrict__ ow,
    const float* __restrict__ ob, float* __restrict__ out)
{
    __shared__ float pooled[128];
    const int b = blockIdx.x;
    const int tid = threadIdx.x;
    if (tid < 128) {
        float s = 0.f;
        for (int tile = 0; tile < 128; ++tile) s += part[(b * 128 + tile) * 128 + tid];
        pooled[tid] = s * (1.f / (float)T_);
    }
    __syncthreads();
    for (int o = tid; o < DIMX; o += 256) {
        float acc = ob[o];
#pragma unroll 4
        for (int d = 0; d < 128; ++d) acc += pooled[d] * ow[d * DIMX + o];
        out[b * DIMX + o] = acc;
    }
}

extern "C" void kernel_launch(void* const* d_in, const int* in_sizes, int n_in,
                              void* d_out, int out_size, void* d_ws, size_t ws_size,
                              hipStream_t stream)
{
    const float* x         = (const float*)d_in[0];
    const float* in_w      = (const float*)d_in[1];
    const float* in_b      = (const float*)d_in[2];
    const float* norm_w    = (const float*)d_in[3];
    const float* inproj_w  = (const float*)d_in[4];
    const float* conv_w    = (const float*)d_in[5];
    const float* conv_b    = (const float*)d_in[6];
    const float* A_log     = (const float*)d_in[7];
    const float* Dvec      = (const float*)d_in[8];
    const float* dt_bias   = (const float*)d_in[9];
    const float* gnorm_w   = (const float*)d_in[10];
    const float* outproj_w = (const float*)d_in[11];
    const float* normf_w   = (const float*)d_in[12];
    const float* out_w     = (const float*)d_in[13];
    const float* out_b     = (const float*)d_in[14];

    float* ws    = (float*)d_ws;
    float* h     = ws + OFF_H;
    float* proj  = ws + OFF_PROJ;
    float* hbc   = ws + OFF_HBC;
    float* ybuf  = ws + OFF_Y;
    float* dtp   = ws + OFF_DTP;
    float* cumb  = ws + OFF_CUM;
    float* zbuf  = ws + OFF_Z;
    float* dec   = ws + OFF_DEC;
    float* part  = ws + OFF_PART;
    ushort_t* wt_in  = (ushort_t*)(ws + OFF_WTIN);
    ushort_t* wt_inp = (ushort_t*)(ws + OFF_WTINP);
    ushort_t* wt_out = (ushort_t*)(ws + OFF_WTOUT);

    k_wt_all<<<68, 256, 0, stream>>>(in_w, inproj_w, outproj_w, wt_in, wt_inp, wt_out);

    k_gemm<512, 128, 0, 1, false><<<dim3(MTOK / 64, 2), 256, 0, stream>>>(x, wt_in, in_b, h);

    for (int l = 0; l < LLAYERS; ++l) {
        k_gemm_rms<<<dim3(MTOK / 64, 9), 256, 0, stream>>>(
            h, norm_w + l * DM, wt_inp + l * 576 * 128, proj);
        k_convdt<<<(MTOK * CONVDIM) / 256 + B_ * NH * NC, 256, 0, stream>>>(
            proj, conv_w, conv_b, A_log, dt_bias, hbc, dtp, cumb, l);
        k_ssd_state<<<B_ * NH * NC, 256, 0, stream>>>(hbc, dtp, cumb, zbuf, dec);
        k_ssd_y<<<B_ * NH * NC, 256, 0, stream>>>(hbc, dtp, cumb, zbuf, dec, Dvec, ybuf, l);
        k_gemm_gn<<<dim3(MTOK / 64, 2), 256, 0, stream>>>(
            ybuf, proj, gnorm_w + l * DINNER, wt_out + l * 128 * 256, h);
    }

    k_finalnorm_pool<<<B_ * (T_ / 16), 256, 0, stream>>>(h, normf_w, part);
    k_head<<<B_, 256, 0, stream>>>(part, out_w, out_b, (float*)d_out);
}

// Round 4
// 277.362 us; speedup vs baseline: 2.4557x; 1.0790x over previous
//
#include <hip/hip_runtime.h>
#include <math.h>

typedef unsigned short ushort_t;
typedef unsigned int uint_t;

// Problem constants
#define B_      8
#define T_      2048
#define DIMX    512
#define DM      128
#define DINNER  256
#define NSTATE  16
#define HDIM    64
#define NH      4
#define CONVDIM 288
#define PROJ    548
#define KCONV   4
#define LLAYERS 2
#define QCH     128
#define NC      (T_/QCH)
#define EPSF    1e-5f
#define MTOK    (B_*T_)

// ---- workspace layout (float offsets) ----
#define OFF_H      0u
#define OFF_DTP    19988480u
#define OFF_CUM    20054016u
#define OFF_Z      20119552u
#define OFF_DEC    21168128u
#define OFF_PART   21168640u
#define OFF_WTIN   23396864u
#define OFF_WTINP  23429632u
#define OFF_WTOUT  23503360u
// NEW: bf16 intermediates (proj gate+xBC, hbc, y) + fp32 dt slice
#define OFF_PROJB  23600000u   // ushort[MTOK*544]  -> 4456448 floats
#define OFF_DTRAW  28100000u   // float [MTOK*4]    -> 65536 floats
#define OFF_HBCB   28200000u   // ushort[MTOK*288]  -> 2359296 floats
#define OFF_YB     30600000u   // ushort[MTOK*256]  -> 2097152 floats (ends ~130.8MB < ws)

__device__ __forceinline__ ushort_t f2b(float f) {
    uint_t u = __builtin_bit_cast(uint_t, f);
    return (ushort_t)((u + 0x7FFFu + ((u >> 16) & 1u)) >> 16);
}
__device__ __forceinline__ float b2f(ushort_t b) {
    uint_t u = ((uint_t)b) << 16;
    return __builtin_bit_cast(float, u);
}
__device__ __forceinline__ float blo(uint_t u) { return b2f((ushort_t)(u & 0xffffu)); }
__device__ __forceinline__ float bhi(uint_t u) { return b2f((ushort_t)(u >> 16)); }

typedef short bf8 __attribute__((ext_vector_type(8)));
typedef float f4v __attribute__((ext_vector_type(4)));

// ===== all weight transposes in ONE kernel (proven r8) =====
__global__ __launch_bounds__(256) void k_wt_all(
    const float* __restrict__ in_w, const float* __restrict__ inproj_w,
    const float* __restrict__ outproj_w,
    ushort_t* __restrict__ wt_in, ushort_t* __restrict__ wt_inp,
    ushort_t* __restrict__ wt_out)
{
    __shared__ float tile[64][65];
    int idx = blockIdx.x;
    const float* W; ushort_t* Wt; int K, N, k0, n0;
    if (idx < 16) {
        W = in_w; Wt = wt_in; K = 512; N = 128;
        k0 = (idx & 7) * 64; n0 = (idx >> 3) * 64;
    } else if (idx < 52) {
        int r = idx - 16; int l = r / 18; r -= l * 18;
        W = inproj_w + l * 128 * PROJ; Wt = wt_inp + l * 576 * 128; K = 128; N = PROJ;
        k0 = (r & 1) * 64; n0 = (r >> 1) * 64;
    } else {
        int r = idx - 52; int l = r / 8; r -= l * 8;
        W = outproj_w + l * 256 * 128; Wt = wt_out + l * 128 * 256; K = 256; N = 128;
        k0 = (r & 3) * 64; n0 = (r >> 2) * 64;
    }
    const int tid = threadIdx.x;
#pragma unroll
    for (int it = 0; it < 16; ++it) {
        const int e = it * 256 + tid;
        const int kk = e >> 6, nn = e & 63;
        tile[kk][nn] = (n0 + nn < N) ? W[(k0 + kk) * N + (n0 + nn)] : 0.f;
    }
    __syncthreads();
#pragma unroll
    for (int it = 0; it < 16; ++it) {
        const int e = it * 256 + tid;
        const int nn = e >> 6, kk = e & 63;
        Wt[(n0 + nn) * K + k0 + kk] = f2b(tile[kk][nn]);
    }
}

// ===== MFMA GEMM (proven r8) — input projection only =====
template<int KTOT, int LDC, int NGUARD, int EPI, bool ABF16>
__global__ __launch_bounds__(256) void k_gemm(
    const void* __restrict__ Ap, const ushort_t* __restrict__ Bt,
    const float* __restrict__ aux, float* __restrict__ C)
{
    __shared__ ushort_t Als[64 * 136];
    __shared__ ushort_t Bls[64 * 136];
    const int m0 = blockIdx.x * 64, n0 = blockIdx.y * 64;
    const int tid = threadIdx.x;
    const int lane = tid & 63, w = tid >> 6;
    const int wm = (w >> 1) * 32, wn = (w & 1) * 32;
    const int r16 = lane & 15, q8 = (lane >> 4) * 8;

    f4v acc[2][2];
#pragma unroll
    for (int i = 0; i < 2; ++i)
#pragma unroll
        for (int j = 0; j < 2; ++j) acc[i][j] = (f4v)0.f;

    for (int kc = 0; kc < KTOT; kc += 128) {
        if constexpr (ABF16) {
            const ushort_t* A = (const ushort_t*)Ap;
#pragma unroll
            for (int i = 0; i < 4; ++i) {
                const int e = i * 2048 + tid * 8;
                const int r = e >> 7, c = e & 127;
                *(uint4*)&Als[r * 136 + c] = *(const uint4*)&A[(m0 + r) * KTOT + kc + c];
            }
        } else {
            const float* A = (const float*)Ap;
#pragma unroll
            for (int i = 0; i < 4; ++i) {
                const int e = i * 2048 + tid * 8;
                const int r = e >> 7, c = e & 127;
                const float4 f0 = *(const float4*)&A[(m0 + r) * KTOT + kc + c];
                const float4 f1 = *(const float4*)&A[(m0 + r) * KTOT + kc + c + 4];
                uint4 pk;
                pk.x = (uint_t)f2b(f0.x) | ((uint_t)f2b(f0.y) << 16);
                pk.y = (uint_t)f2b(f0.z) | ((uint_t)f2b(f0.w) << 16);
                pk.z = (uint_t)f2b(f1.x) | ((uint_t)f2b(f1.y) << 16);
                pk.w = (uint_t)f2b(f1.z) | ((uint_t)f2b(f1.w) << 16);
                *(uint4*)&Als[r * 136 + c] = pk;
            }
        }
#pragma unroll
        for (int i = 0; i < 4; ++i) {
            const int e = i * 2048 + tid * 8;
            const int r = e >> 7, c = e & 127;
            *(uint4*)&Bls[r * 136 + c] = *(const uint4*)&Bt[(n0 + r) * KTOT + kc + c];
        }
        __syncthreads();
#pragma unroll
        for (int kk = 0; kk < 128; kk += 32) {
            const bf8 a0 = *(const bf8*)&Als[(wm + r16) * 136 + kk + q8];
            const bf8 a1 = *(const bf8*)&Als[(wm + 16 + r16) * 136 + kk + q8];
            const bf8 b0 = *(const bf8*)&Bls[(wn + r16) * 136 + kk + q8];
            const bf8 b1 = *(const bf8*)&Bls[(wn + 16 + r16) * 136 + kk + q8];
            acc[0][0] = __builtin_amdgcn_mfma_f32_16x16x32_bf16(a0, b0, acc[0][0], 0, 0, 0);
            acc[0][1] = __builtin_amdgcn_mfma_f32_16x16x32_bf16(a0, b1, acc[0][1], 0, 0, 0);
            acc[1][0] = __builtin_amdgcn_mfma_f32_16x16x32_bf16(a1, b0, acc[1][0], 0, 0, 0);
            acc[1][1] = __builtin_amdgcn_mfma_f32_16x16x32_bf16(a1, b1, acc[1][1], 0, 0, 0);
        }
        __syncthreads();
    }
    const int q4 = (lane >> 4) * 4;
#pragma unroll
    for (int i = 0; i < 2; ++i)
#pragma unroll
        for (int j = 0; j < 2; ++j)
#pragma unroll
            for (int r = 0; r < 4; ++r) {
                const int grow = m0 + wm + i * 16 + q4 + r;
                const int gcol = n0 + wn + j * 16 + r16;
                if (NGUARD == 0 || gcol < NGUARD) {
                    float v = acc[i][j][r];
                    if (EPI == 1) v += aux[gcol];
                    if (EPI == 2) v += C[grow * LDC + gcol];
                    C[grow * LDC + gcol] = v;
                }
            }
}

// ===== inproj GEMM + inline RMSNorm; epilogue -> bf16 projb + fp32 dtraw =====
__global__ __launch_bounds__(256) void k_gemm_rms(
    const float* __restrict__ h, const float* __restrict__ nw,
    const ushort_t* __restrict__ Bt, ushort_t* __restrict__ projb,
    float* __restrict__ dtraw)
{
    __shared__ ushort_t Als[64 * 136];
    __shared__ ushort_t Bls[64 * 136];
    const int m0 = blockIdx.x * 64, n0 = blockIdx.y * 64;
    const int tid = threadIdx.x;
    const int lane = tid & 63, w = tid >> 6;
    const int wm = (w >> 1) * 32, wn = (w & 1) * 32;
    const int r16 = lane & 15, q8 = (lane >> 4) * 8;

#pragma unroll
    for (int i = 0; i < 4; ++i) {
        const int e = i * 2048 + tid * 8;
        const int r = e >> 7, c = e & 127;
        const float4 f0 = *(const float4*)&h[(m0 + r) * 128 + c];
        const float4 f1 = *(const float4*)&h[(m0 + r) * 128 + c + 4];
        float ss = f0.x * f0.x + f0.y * f0.y + f0.z * f0.z + f0.w * f0.w
                 + f1.x * f1.x + f1.y * f1.y + f1.z * f1.z + f1.w * f1.w;
#pragma unroll
        for (int off = 1; off < 16; off <<= 1) ss += __shfl_xor(ss, off);
        const float rs = rsqrtf(ss * (1.f / 128.f) + EPSF);
        const float4 w0 = *(const float4*)&nw[c];
        const float4 w1 = *(const float4*)&nw[c + 4];
        uint4 pk;
        pk.x = (uint_t)f2b(f0.x * rs * w0.x) | ((uint_t)f2b(f0.y * rs * w0.y) << 16);
        pk.y = (uint_t)f2b(f0.z * rs * w0.z) | ((uint_t)f2b(f0.w * rs * w0.w) << 16);
        pk.z = (uint_t)f2b(f1.x * rs * w1.x) | ((uint_t)f2b(f1.y * rs * w1.y) << 16);
        pk.w = (uint_t)f2b(f1.z * rs * w1.z) | ((uint_t)f2b(f1.w * rs * w1.w) << 16);
        *(uint4*)&Als[r * 136 + c] = pk;
    }
#pragma unroll
    for (int i = 0; i < 4; ++i) {
        const int e = i * 2048 + tid * 8;
        const int r = e >> 7, c = e & 127;
        *(uint4*)&Bls[r * 136 + c] = *(const uint4*)&Bt[(n0 + r) * 128 + c];
    }
    __syncthreads();

    f4v acc[2][2];
#pragma unroll
    for (int i = 0; i < 2; ++i)
#pragma unroll
        for (int j = 0; j < 2; ++j) acc[i][j] = (f4v)0.f;
#pragma unroll
    for (int kk = 0; kk < 128; kk += 32) {
        const bf8 a0 = *(const bf8*)&Als[(wm + r16) * 136 + kk + q8];
        const bf8 a1 = *(const bf8*)&Als[(wm + 16 + r16) * 136 + kk + q8];
        const bf8 b0 = *(const bf8*)&Bls[(wn + r16) * 136 + kk + q8];
        const bf8 b1 = *(const bf8*)&Bls[(wn + 16 + r16) * 136 + kk + q8];
        acc[0][0] = __builtin_amdgcn_mfma_f32_16x16x32_bf16(a0, b0, acc[0][0], 0, 0, 0);
        acc[0][1] = __builtin_amdgcn_mfma_f32_16x16x32_bf16(a0, b1, acc[0][1], 0, 0, 0);
        acc[1][0] = __builtin_amdgcn_mfma_f32_16x16x32_bf16(a1, b0, acc[1][0], 0, 0, 0);
        acc[1][1] = __builtin_amdgcn_mfma_f32_16x16x32_bf16(a1, b1, acc[1][1], 0, 0, 0);
    }

    const int q4 = (lane >> 4) * 4;
#pragma unroll
    for (int i = 0; i < 2; ++i)
#pragma unroll
        for (int j = 0; j < 2; ++j)
#pragma unroll
            for (int r = 0; r < 4; ++r) {
                const int grow = m0 + wm + i * 16 + q4 + r;
                const int gcol = n0 + wn + j * 16 + r16;
                if (gcol < 544) projb[grow * 544 + gcol] = f2b(acc[i][j][r]);
                else if (gcol < PROJ) dtraw[grow * 4 + (gcol - 544)] = acc[i][j][r];
            }
}

// ===== outproj GEMM + inline gated-RMSNorm on bf16 y / bf16 gate =====
__global__ __launch_bounds__(256) void k_gemm_gn(
    const ushort_t* __restrict__ yb, const ushort_t* __restrict__ projb,
    const float* __restrict__ gw, const ushort_t* __restrict__ Bt,
    float* __restrict__ C)
{
    __shared__ ushort_t Als[64 * 264];
    __shared__ ushort_t Bls[64 * 136];
    const int m0 = blockIdx.x * 64, n0 = blockIdx.y * 64;
    const int tid = threadIdx.x;
    const int lane = tid & 63, w = tid >> 6;
    const int wm = (w >> 1) * 32, wn = (w & 1) * 32;
    const int r16 = lane & 15, q8 = (lane >> 4) * 8;

#pragma unroll
    for (int i = 0; i < 8; ++i) {
        const int e = i * 2048 + tid * 8;
        const int r = e >> 8, c = e & 255;
        const uint4 yv = *(const uint4*)&yb[(m0 + r) * 256 + c];
        const uint4 gv = *(const uint4*)&projb[(m0 + r) * 544 + c];
        const float g0 = blo(gv.x), g1 = bhi(gv.x), g2 = blo(gv.y), g3 = bhi(gv.y);
        const float g4 = blo(gv.z), g5 = bhi(gv.z), g6 = blo(gv.w), g7 = bhi(gv.w);
        float v0 = blo(yv.x) * (g0 / (1.f + __expf(-g0)));
        float v1 = bhi(yv.x) * (g1 / (1.f + __expf(-g1)));
        float v2 = blo(yv.y) * (g2 / (1.f + __expf(-g2)));
        float v3 = bhi(yv.y) * (g3 / (1.f + __expf(-g3)));
        float v4 = blo(yv.z) * (g4 / (1.f + __expf(-g4)));
        float v5 = bhi(yv.z) * (g5 / (1.f + __expf(-g5)));
        float v6 = blo(yv.w) * (g6 / (1.f + __expf(-g6)));
        float v7 = bhi(yv.w) * (g7 / (1.f + __expf(-g7)));
        float ss = v0 * v0 + v1 * v1 + v2 * v2 + v3 * v3
                 + v4 * v4 + v5 * v5 + v6 * v6 + v7 * v7;
#pragma unroll
        for (int off = 1; off < 32; off <<= 1) ss += __shfl_xor(ss, off);
        const float rs = rsqrtf(ss * (1.f / 256.f) + EPSF);
        const float4 w0 = *(const float4*)&gw[c];
        const float4 w1 = *(const float4*)&gw[c + 4];
        uint4 pk;
        pk.x = (uint_t)f2b(v0 * rs * w0.x) | ((uint_t)f2b(v1 * rs * w0.y) << 16);
        pk.y = (uint_t)f2b(v2 * rs * w0.z) | ((uint_t)f2b(v3 * rs * w0.w) << 16);
        pk.z = (uint_t)f2b(v4 * rs * w1.x) | ((uint_t)f2b(v5 * rs * w1.y) << 16);
        pk.w = (uint_t)f2b(v6 * rs * w1.z) | ((uint_t)f2b(v7 * rs * w1.w) << 16);
        *(uint4*)&Als[r * 264 + c] = pk;
    }

    f4v acc[2][2];
#pragma unroll
    for (int i = 0; i < 2; ++i)
#pragma unroll
        for (int j = 0; j < 2; ++j) acc[i][j] = (f4v)0.f;

    for (int kc = 0; kc < 256; kc += 128) {
#pragma unroll
        for (int i = 0; i < 4; ++i) {
            const int e = i * 2048 + tid * 8;
            const int r = e >> 7, c = e & 127;
            *(uint4*)&Bls[r * 136 + c] = *(const uint4*)&Bt[(n0 + r) * 256 + kc + c];
        }
        __syncthreads();
#pragma unroll
        for (int kk = 0; kk < 128; kk += 32) {
            const bf8 a0 = *(const bf8*)&Als[(wm + r16) * 264 + kc + kk + q8];
            const bf8 a1 = *(const bf8*)&Als[(wm + 16 + r16) * 264 + kc + kk + q8];
            const bf8 b0 = *(const bf8*)&Bls[(wn + r16) * 136 + kk + q8];
            const bf8 b1 = *(const bf8*)&Bls[(wn + 16 + r16) * 136 + kk + q8];
            acc[0][0] = __builtin_amdgcn_mfma_f32_16x16x32_bf16(a0, b0, acc[0][0], 0, 0, 0);
            acc[0][1] = __builtin_amdgcn_mfma_f32_16x16x32_bf16(a0, b1, acc[0][1], 0, 0, 0);
            acc[1][0] = __builtin_amdgcn_mfma_f32_16x16x32_bf16(a1, b0, acc[1][0], 0, 0, 0);
            acc[1][1] = __builtin_amdgcn_mfma_f32_16x16x32_bf16(a1, b1, acc[1][1], 0, 0, 0);
        }
        __syncthreads();
    }

    const int q4 = (lane >> 4) * 4;
#pragma unroll
    for (int i = 0; i < 2; ++i)
#pragma unroll
        for (int j = 0; j < 2; ++j)
#pragma unroll
            for (int r = 0; r < 4; ++r) {
                const int grow = m0 + wm + i * 16 + q4 + r;
                const int gcol = n0 + wn + j * 16 + r16;
                C[grow * 128 + gcol] += acc[i][j][r];
            }
}

// ===== conv + dtprep merged; reads bf16 projb / fp32 dtraw, writes bf16 hbcb =====
__global__ __launch_bounds__(256) void k_convdt(
    const ushort_t* __restrict__ projb, const float* __restrict__ dtraw,
    const float* __restrict__ cw, const float* __restrict__ cb,
    const float* __restrict__ A_log, const float* __restrict__ dt_bias,
    ushort_t* __restrict__ hbcb, float* __restrict__ dtp,
    float* __restrict__ cum, int l)
{
    __shared__ float sc[128];
    const int bid = blockIdx.x;
    const int tid = threadIdx.x;
    if (bid < (MTOK * CONVDIM) / 256) {
        const int e = bid * 256 + tid;
        const int m = e / CONVDIM;
        const int cch = e - m * CONVDIM;
        const int b = m >> 11;
        const int t = m & (T_ - 1);
        const float* wp = cw + (l * CONVDIM + cch) * KCONV;
        float acc = cb[l * CONVDIM + cch];
#pragma unroll
        for (int k = 0; k < KCONV; ++k) {
            const int tt = t - (KCONV - 1) + k;
            if (tt >= 0) acc += b2f(projb[(b * T_ + tt) * 544 + 256 + cch]) * wp[k];
        }
        hbcb[m * CONVDIM + cch] = f2b(acc / (1.f + __expf(-acc)));
    } else {
        const int bid2 = bid - (MTOK * CONVDIM) / 256;
        const int c = bid2 & (NC - 1);
        const int hh = (bid2 / NC) & (NH - 1);
        const int b = bid2 / (NC * NH);
        const int t = tid;
        float dtv = 0.f;
        if (t < 128) {
            const int m = b * T_ + c * QCH + t;
            const float Ah = -expf(A_log[l * NH + hh]);
            const float raw = dtraw[m * 4 + hh] + dt_bias[l * NH + hh];
            dtv = (raw > 20.f) ? raw : log1pf(expf(raw));
            sc[t] = dtv * Ah;
        }
        __syncthreads();
        for (int off = 1; off < 128; off <<= 1) {
            const float v = (t >= off && t < 128) ? sc[t - off] : 0.f;
            __syncthreads();
            if (t < 128) sc[t] += v;
            __syncthreads();
        }
        if (t < 128) {
            const int m = b * T_ + c * QCH + t;
            dtp[m * NH + hh] = dtv;
            cum[m * NH + hh] = sc[t];
        }
    }
}

// ===== SSD chunk state; X/B/C from bf16 hbcb (X copy is bit-identical) =====
__global__ __launch_bounds__(256) void k_ssd_state(
    const ushort_t* __restrict__ hbcb, const float* __restrict__ dtp,
    const float* __restrict__ cum, float* __restrict__ zbuf,
    float* __restrict__ dec)
{
    __shared__ ushort_t Xt[64 * 136];
    __shared__ ushort_t wB[16 * 136];
    __shared__ float cumls[QCH];
    __shared__ float dtls[QCH];
    const int bid = blockIdx.x;
    const int c = bid & (NC - 1);
    const int hh = (bid / NC) & (NH - 1);
    const int b = bid / (NC * NH);
    const int m0 = b * T_ + c * QCH;
    const int tid = threadIdx.x;

    if (tid < QCH) {
        cumls[tid] = cum[(m0 + tid) * NH + hh];
        dtls[tid] = dtp[(m0 + tid) * NH + hh];
    }
    __syncthreads();
    const float clast = cumls[QCH - 1];
    {
        const int p = tid & 63;
        const int s0 = tid >> 6;
#pragma unroll
        for (int pass = 0; pass < 32; ++pass) {
            const int s = s0 + pass * 4;
            Xt[p * 136 + s] = hbcb[(m0 + s) * CONVDIM + hh * 64 + p];
        }
    }
    for (int e = tid; e < QCH * 16; e += 256) {
        const int n = e & 15, s = e >> 4;
        const float w = __expf(clast - cumls[s]) * dtls[s];
        wB[n * 136 + s] = f2b(w * b2f(hbcb[(m0 + s) * CONVDIM + DINNER + n]));
    }
    __syncthreads();

    const int lane = tid & 63, w = tid >> 6;
    const int r16 = lane & 15, q8 = (lane >> 4) * 8, q4 = (lane >> 4) * 4;
    f4v acc = (f4v)0.f;
#pragma unroll
    for (int kc = 0; kc < 128; kc += 32) {
        const bf8 a = *(const bf8*)&Xt[(w * 16 + r16) * 136 + kc + q8];
        const bf8 bb = *(const bf8*)&wB[r16 * 136 + kc + q8];
        acc = __builtin_amdgcn_mfma_f32_16x16x32_bf16(a, bb, acc, 0, 0, 0);
    }
#pragma unroll
    for (int r = 0; r < 4; ++r) {
        const int p = w * 16 + q4 + r;
        zbuf[bid * 1024 + p * 16 + r16] = acc[r];
    }
    if (tid == 0) dec[bid] = __expf(clast);
}

// ===== fused SSD y + per-block inter-chunk scan; bf16 in, bf16 out =====
__global__ __launch_bounds__(256) void k_ssd_y(
    const ushort_t* __restrict__ hbcb, const float* __restrict__ dtp,
    const float* __restrict__ cum, const float* __restrict__ zbuf,
    const float* __restrict__ dec, const float* __restrict__ Dvec,
    ushort_t* __restrict__ yb, int l)
{
    __shared__ ushort_t Xt[64 * 136];
    __shared__ ushort_t BlsT[128 * 40];
    __shared__ ushort_t ClsT[128 * 40];
    __shared__ ushort_t Gls[128 * 136];
    __shared__ ushort_t Spt[64 * 40];
    __shared__ float cumls[QCH];
    __shared__ float dtls[QCH];
    const int bid = blockIdx.x;
    const int c = bid & (NC - 1);
    const int hh = (bid / NC) & (NH - 1);
    const int b = bid / (NC * NH);
    const int bh = bid >> 4;           // = b*NH + hh  (NC == 16)
    const int m0 = b * T_ + c * QCH;
    const int tid = threadIdx.x;

    if (tid < QCH) {
        cumls[tid] = cum[(m0 + tid) * NH + hh];
        dtls[tid] = dtp[(m0 + tid) * NH + hh];
    }
    {
        const int p = tid & 63;
        const int s0 = tid >> 6;
#pragma unroll
        for (int pass = 0; pass < 32; ++pass) {
            const int s = s0 + pass * 4;
            Xt[p * 136 + s] = hbcb[(m0 + s) * CONVDIM + hh * 64 + p];
        }
    }
    for (int e = tid; e < QCH * 16; e += 256) {
        const int n = e & 15, s = e >> 4;
        BlsT[s * 40 + n] = hbcb[(m0 + s) * CONVDIM + DINNER + n];
        BlsT[s * 40 + 16 + n] = 0;
        ClsT[s * 40 + n] = hbcb[(m0 + s) * CONVDIM + DINNER + NSTATE + n];
        ClsT[s * 40 + 16 + n] = 0;
    }
    // per-block prefix scan over earlier chunks (replaces k_state_scan)
    {
        float4 S; S.x = 0.f; S.y = 0.f; S.z = 0.f; S.w = 0.f;
        for (int cc = 0; cc < c; ++cc) {
            const float d = dec[bh * NC + cc];
            const float4 z = *(const float4*)(zbuf + (bh * NC + cc) * 1024 + tid * 4);
            S.x = S.x * d + z.x; S.y = S.y * d + z.y;
            S.z = S.z * d + z.z; S.w = S.w * d + z.w;
        }
        const int p = tid >> 2, n = (tid & 3) * 4;
        Spt[p * 40 + n]     = f2b(S.x);
        Spt[p * 40 + n + 1] = f2b(S.y);
        Spt[p * 40 + n + 2] = f2b(S.z);
        Spt[p * 40 + n + 3] = f2b(S.w);
        Spt[p * 40 + 16 + n]     = 0;
        Spt[p * 40 + 16 + n + 1] = 0;
        Spt[p * 40 + 16 + n + 2] = 0;
        Spt[p * 40 + 16 + n + 3] = 0;
    }
    __syncthreads();

    const int lane = tid & 63, w = tid >> 6;
    const int wrow = w * 32;
    const int r16 = lane & 15, q8 = (lane >> 4) * 8, q4 = (lane >> 4) * 4;
    const float Dh = Dvec[l * NH + hh];

    bf8 cfr[2];
#pragma unroll
    for (int i = 0; i < 2; ++i)
        cfr[i] = *(const bf8*)&ClsT[(wrow + i * 16 + r16) * 40 + q8];

    float cumt[8], et[8];
#pragma unroll
    for (int i = 0; i < 2; ++i)
#pragma unroll
        for (int r = 0; r < 4; ++r) {
            const int t = wrow + i * 16 + q4 + r;
            cumt[i * 4 + r] = cumls[t];
            et[i * 4 + r] = __expf(cumls[t]);
        }

    f4v acc[2][4];
#pragma unroll
    for (int j = 0; j < 4; ++j) {
        const bf8 sf = *(const bf8*)&Spt[(j * 16 + r16) * 40 + q8];
#pragma unroll
        for (int i = 0; i < 2; ++i) {
            f4v z = (f4v)0.f;
            z = __builtin_amdgcn_mfma_f32_16x16x32_bf16(cfr[i], sf, z, 0, 0, 0);
#pragma unroll
            for (int r = 0; r < 4; ++r) {
                const int t = wrow + i * 16 + q4 + r;
                const int p = j * 16 + r16;
                acc[i][j][r] = z[r] * et[i * 4 + r] + Dh * b2f(Xt[p * 136 + t]);
            }
        }
    }

#pragma unroll
    for (int ts = 0; ts < 8; ++ts) {
        const bf8 bf = *(const bf8*)&BlsT[(ts * 16 + r16) * 40 + q8];
        const int s = ts * 16 + r16;
        const float cs = cumls[s];
        const float ds = dtls[s];
#pragma unroll
        for (int i = 0; i < 2; ++i) {
            f4v g = (f4v)0.f;
            g = __builtin_amdgcn_mfma_f32_16x16x32_bf16(cfr[i], bf, g, 0, 0, 0);
#pragma unroll
            for (int r = 0; r < 4; ++r) {
                const int t = wrow + i * 16 + q4 + r;
                const float val = (s <= t) ? __expf(cumt[i * 4 + r] - cs) * ds * g[r] : 0.f;
                Gls[t * 136 + s] = f2b(val);
            }
        }
    }
    __syncthreads();

#pragma unroll
    for (int kc = 0; kc < 128; kc += 32) {
        bf8 af[2];
#pragma unroll
        for (int i = 0; i < 2; ++i)
            af[i] = *(const bf8*)&Gls[(wrow + i * 16 + r16) * 136 + kc + q8];
#pragma unroll
        for (int j = 0; j < 4; ++j) {
            const bf8 xf = *(const bf8*)&Xt[(j * 16 + r16) * 136 + kc + q8];
#pragma unroll
            for (int i = 0; i < 2; ++i)
                acc[i][j] = __builtin_amdgcn_mfma_f32_16x16x32_bf16(af[i], xf, acc[i][j], 0, 0, 0);
        }
    }

#pragma unroll
    for (int i = 0; i < 2; ++i)
#pragma unroll
        for (int r = 0; r < 4; ++r) {
            const int t = wrow + i * 16 + q4 + r;
#pragma unroll
            for (int j = 0; j < 4; ++j) {
                const int p = j * 16 + r16;
                yb[(m0 + t) * DINNER + hh * 64 + p] = f2b(acc[i][j][r]);
            }
        }
}

// ===== final rmsnorm + partial mean-pool (proven) =====
__global__ __launch_bounds__(256) void k_finalnorm_pool(
    const float* __restrict__ h, const float* __restrict__ nfw,
    float* __restrict__ part)
{
    __shared__ float ht[2048];
    __shared__ float red[256];
    __shared__ float rstd[16];
    __shared__ float padd[256];
    const int tile = blockIdx.x & 127;
    const int b = blockIdx.x >> 7;
    const int m0 = b * T_ + tile * 16;
    const int tid = threadIdx.x;
    for (int e = tid; e < 2048; e += 256) ht[e] = h[m0 * DM + e];
    __syncthreads();
    {
        const int tg = tid >> 4, j0 = tid & 15;
        float p = 0.f;
#pragma unroll
        for (int k = 0; k < 8; ++k) { const float v = ht[tg * 128 + j0 + 16 * k]; p += v * v; }
        red[tid] = p;
    }
    __syncthreads();
    if (tid < 16) {
        float s = 0.f;
#pragma unroll
        for (int q = 0; q < 16; ++q) s += red[tid * 16 + q];
        rstd[tid] = rsqrtf(s * (1.f / 128.f) + EPSF);
    }
    __syncthreads();
    const int d = tid & 127, half = tid >> 7;
    float ps = 0.f;
#pragma unroll
    for (int i0 = 0; i0 < 8; ++i0) { const int i = half + 2 * i0; ps += ht[i * 128 + d] * rstd[i]; }
    padd[tid] = ps;
    __syncthreads();
    if (tid < 128) part[(b * 128 + tile) * 128 + tid] = (padd[tid] + padd[128 + tid]) * nfw[tid];
}

// ===== pooled reduce + head GEMM (proven) =====
__global__ __launch_bounds__(256) void k_head(
    const float* __restrict__ part, const float* __restrict__ ow,
    const float* __restrict__ ob, float* __restrict__ out)
{
    __shared__ float pooled[128];
    const int b = blockIdx.x;
    const int tid = threadIdx.x;
    if (tid < 128) {
        float s = 0.f;
        for (int tile = 0; tile < 128; ++tile) s += part[(b * 128 + tile) * 128 + tid];
        pooled[tid] = s * (1.f / (float)T_);
    }
    __syncthreads();
    for (int o = tid; o < DIMX; o += 256) {
        float acc = ob[o];
#pragma unroll 4
        for (int d = 0; d < 128; ++d) acc += pooled[d] * ow[d * DIMX + o];
        out[b * DIMX + o] = acc;
    }
}

extern "C" void kernel_launch(void* const* d_in, const int* in_sizes, int n_in,
                              void* d_out, int out_size, void* d_ws, size_t ws_size,
                              hipStream_t stream)
{
    const float* x         = (const float*)d_in[0];
    const float* in_w      = (const float*)d_in[1];
    const float* in_b      = (const float*)d_in[2];
    const float* norm_w    = (const float*)d_in[3];
    const float* inproj_w  = (const float*)d_in[4];
    const float* conv_w    = (const float*)d_in[5];
    const float* conv_b    = (const float*)d_in[6];
    const float* A_log     = (const float*)d_in[7];
    const float* Dvec      = (const float*)d_in[8];
    const float* dt_bias   = (const float*)d_in[9];
    const float* gnorm_w   = (const float*)d_in[10];
    const float* outproj_w = (const float*)d_in[11];
    const float* normf_w   = (const float*)d_in[12];
    const float* out_w     = (const float*)d_in[13];
    const float* out_b     = (const float*)d_in[14];

    float* ws    = (float*)d_ws;
    float* h     = ws + OFF_H;
    float* dtp   = ws + OFF_DTP;
    float* cumb  = ws + OFF_CUM;
    float* zbuf  = ws + OFF_Z;
    float* dec   = ws + OFF_DEC;
    float* part  = ws + OFF_PART;
    float* dtraw = ws + OFF_DTRAW;
    ushort_t* projb = (ushort_t*)(ws + OFF_PROJB);
    ushort_t* hbcb  = (ushort_t*)(ws + OFF_HBCB);
    ushort_t* yb    = (ushort_t*)(ws + OFF_YB);
    ushort_t* wt_in  = (ushort_t*)(ws + OFF_WTIN);
    ushort_t* wt_inp = (ushort_t*)(ws + OFF_WTINP);
    ushort_t* wt_out = (ushort_t*)(ws + OFF_WTOUT);

    k_wt_all<<<68, 256, 0, stream>>>(in_w, inproj_w, outproj_w, wt_in, wt_inp, wt_out);

    k_gemm<512, 128, 0, 1, false><<<dim3(MTOK / 64, 2), 256, 0, stream>>>(x, wt_in, in_b, h);

    for (int l = 0; l < LLAYERS; ++l) {
        k_gemm_rms<<<dim3(MTOK / 64, 9), 256, 0, stream>>>(
            h, norm_w + l * DM, wt_inp + l * 576 * 128, projb, dtraw);
        k_convdt<<<(MTOK * CONVDIM) / 256 + B_ * NH * NC, 256, 0, stream>>>(
            projb, dtraw, conv_w, conv_b, A_log, dt_bias, hbcb, dtp, cumb, l);
        k_ssd_state<<<B_ * NH * NC, 256, 0, stream>>>(hbcb, dtp, cumb, zbuf, dec);
        k_ssd_y<<<B_ * NH * NC, 256, 0, stream>>>(hbcb, dtp, cumb, zbuf, dec, Dvec, yb, l);
        k_gemm_gn<<<dim3(MTOK / 64, 2), 256, 0, stream>>>(
            yb, projb, gnorm_w + l * DINNER, wt_out + l * 128 * 256, h);
    }

    k_finalnorm_pool<<<B_ * (T_ / 16), 256, 0, stream>>>(h, normf_w, part);
    k_head<<<B_, 256, 0, stream>>>(part, out_w, out_b, (float*)d_out);
}